// Round 4
// baseline (810.508 us; speedup 1.0000x reference)
//
#include <hip/hip_runtime.h>
#include <hip/hip_bf16.h>
#include <math.h>

#define NN 100000      // nodes
#define NE 1600000     // edges
#define NF 256         // input features
#define NH 128         // hidden
#define NC 40          // classes

// Workspace layout (4-byte units):
//   counts  [0,       100032)
//   offsets [100032,  200128)   (NN+1 used)
//   cursor  [200128,  300160)
//   dinv    [300160,  400192)
//   erec    [400192,  3600192)  (NE int2)
//   H       [3600192, 16400192) (bf16 NN*NH = 12.8M bf16 = 6.4M slots; scan scratch early;
//                                reused as H2 bf16 [NN*NC] after agg1)
//   Hagg    [16400192,29200192) (NN*NH floats)
#define OFF_OFFSETS 100032
#define OFF_CURSOR  200128
#define OFF_DINV    300160
#define OFF_EREC    400192
#define OFF_H       3600192
#define OFF_HAGG    16400192

#define SCAN_TILE 1024
#define SCAN_NB   ((NN + SCAN_TILE - 1) / SCAN_TILE)   // 98

// ---------------- CSR build ----------------
__global__ void count_kernel(const int* __restrict__ dst, int* __restrict__ count) {
    int t = blockIdx.x * blockDim.x + threadIdx.x;
    if (t < NE) atomicAdd(&count[dst[t]], 1);
}

__global__ void dinv_kernel(const int* __restrict__ count, float* __restrict__ dinv) {
    int t = blockIdx.x * blockDim.x + threadIdx.x;
    if (t < NN) dinv[t] = rsqrtf((float)count[t] + 1.0f);  // +1 self loop
}

// ---- hierarchical scan: phase 1 — per-tile reduce ----
__global__ void scan_phase1(const int* __restrict__ count, int* __restrict__ blocksums) {
    int b = blockIdx.x, t = threadIdx.x;
    int i = b * SCAN_TILE + t;
    int v = (i < NN) ? count[i] : 0;
    #pragma unroll
    for (int off = 32; off; off >>= 1) v += __shfl_xor(v, off, 64);
    __shared__ int ws[16];
    int lane = t & 63, wave = t >> 6;
    if (lane == 0) ws[wave] = v;
    __syncthreads();
    if (t == 0) {
        int s = 0;
        #pragma unroll
        for (int w = 0; w < SCAN_TILE / 64; ++w) s += ws[w];
        blocksums[b] = s;
    }
}

// ---- phase 2 — scan the 98 block sums ----
__global__ void scan_phase2(const int* __restrict__ blocksums, int* __restrict__ blockpref) {
    __shared__ int s[128];
    int t = threadIdx.x;
    int v = (t < SCAN_NB) ? blocksums[t] : 0;
    s[t] = v;
    __syncthreads();
    for (int off = 1; off < 128; off <<= 1) {
        int u = (t >= off) ? s[t - off] : 0;
        __syncthreads();
        s[t] += u;
        __syncthreads();
    }
    if (t < SCAN_NB) blockpref[t] = s[t] - v;   // exclusive prefix
}

// ---- phase 3 — in-tile exclusive scan + block prefix -> offsets & cursor ----
__global__ void scan_phase3(const int* __restrict__ count, const int* __restrict__ blockpref,
                            int* __restrict__ offsets, int* __restrict__ cursor) {
    int b = blockIdx.x, t = threadIdx.x;
    int i = b * SCAN_TILE + t;
    int v = (i < NN) ? count[i] : 0;
    int lane = t & 63, wave = t >> 6;
    int s = v;
    #pragma unroll
    for (int off = 1; off < 64; off <<= 1) {
        int u = __shfl_up(s, off, 64);
        if (lane >= off) s += u;
    }
    __shared__ int wsum[16];
    if (lane == 63) wsum[wave] = s;
    __syncthreads();
    if (t < 16) {
        int x = wsum[t];
        #pragma unroll
        for (int off = 1; off < 16; off <<= 1) {
            int u = __shfl_up(x, off, 64);
            if (t >= off) x += u;
        }
        wsum[t] = x;
    }
    __syncthreads();
    int excl = (s - v) + (wave ? wsum[wave - 1] : 0) + blockpref[b];
    if (i < NN) {
        offsets[i] = excl;
        cursor[i]  = excl;
        if (i == NN - 1) offsets[NN] = excl + v;
    }
}

// counting-sort edges into dst buckets; record (src, weight)
__global__ void bucket_kernel(const int* __restrict__ ei, const float* __restrict__ dinv,
                              int* __restrict__ cursor, int2* __restrict__ erec) {
    int t = blockIdx.x * blockDim.x + threadIdx.x;
    if (t >= NE) return;
    int s = ei[t];
    int d = ei[NE + t];
    int pos = atomicAdd(&cursor[d], 1);
    float w = dinv[s] * dinv[d];
    erec[pos] = make_int2(s, __float_as_int(w));
}

// ---------------- register-tiled fp32 GEMM, bf16 output ----------------
template<int BM, int BN, int BK, int TM, int TN>
__global__ void gemm_f32_bf16out(const float* __restrict__ A, const float* __restrict__ B,
                                 __hip_bfloat16* __restrict__ C, int M, int N, int K) {
    constexpr int THREADS = (BM / TM) * (BN / TN);
    __shared__ float sA[BK][BM + 1];
    __shared__ float sB[BK][BN];
    const int tid  = threadIdx.x;
    const int tcol = tid % (BN / TN);
    const int trow = tid / (BN / TN);
    const int row0 = blockIdx.y * BM;
    const int col0 = blockIdx.x * BN;

    float acc[TM][TN];
    #pragma unroll
    for (int i = 0; i < TM; ++i)
        #pragma unroll
        for (int j = 0; j < TN; ++j) acc[i][j] = 0.f;

    for (int k0 = 0; k0 < K; k0 += BK) {
        #pragma unroll
        for (int idx = tid; idx < BM * BK; idx += THREADS) {
            int m = idx / BK, kk = idx % BK;
            int r = row0 + m;
            sA[kk][m] = (r < M) ? A[(size_t)r * K + k0 + kk] : 0.f;
        }
        #pragma unroll
        for (int idx = tid; idx < BK * BN; idx += THREADS) {
            int kk = idx / BN, n = idx % BN;
            int c = col0 + n;
            sB[kk][n] = (c < N) ? B[(size_t)(k0 + kk) * N + c] : 0.f;
        }
        __syncthreads();
        #pragma unroll
        for (int kk = 0; kk < BK; ++kk) {
            float a[TM], b[TN];
            #pragma unroll
            for (int i = 0; i < TM; ++i) a[i] = sA[kk][trow * TM + i];
            #pragma unroll
            for (int j = 0; j < TN; ++j) b[j] = sB[kk][tcol * TN + j];
            #pragma unroll
            for (int i = 0; i < TM; ++i)
                #pragma unroll
                for (int j = 0; j < TN; ++j) acc[i][j] += a[i] * b[j];
        }
        __syncthreads();
    }

    #pragma unroll
    for (int i = 0; i < TM; ++i) {
        int r = row0 + trow * TM + i;
        if (r >= M) continue;
        #pragma unroll
        for (int j = 0; j < TN; ++j) {
            int c = col0 + tcol * TN + j;
            if (c < N) C[(size_t)r * N + c] = __float2bfloat16(acc[i][j]);
        }
    }
}

// ---------------- layer-1 gather (bf16 rows): one wave per dst node, fused self+bias+relu ----------------
__global__ void agg1_gather(const int* __restrict__ offsets, const int2* __restrict__ erec,
                            const float* __restrict__ dinv, const __hip_bfloat16* __restrict__ H,
                            const float* __restrict__ b1, float* __restrict__ Hagg) {
    int gw = (blockIdx.x * blockDim.x + threadIdx.x) >> 6;   // node
    if (gw >= NN) return;
    int lane = threadIdx.x & 63;
    int beg = offsets[gw], end = offsets[gw + 1];
    const __hip_bfloat162* H2v = reinterpret_cast<const __hip_bfloat162*>(H);
    float2 acc = make_float2(0.f, 0.f);
    for (int p = beg; p < end; ++p) {
        int2 r = erec[p];                       // wave-uniform address -> broadcast
        float w = __int_as_float(r.y);
        float2 hv = __bfloat1622float2(H2v[(size_t)r.x * (NH / 2) + lane]);
        acc.x += hv.x * w;
        acc.y += hv.y * w;
    }
    float di = dinv[gw];
    float sl = di * di;
    float2 hs = __bfloat1622float2(H2v[(size_t)gw * (NH / 2) + lane]);
    float2 bb = *reinterpret_cast<const float2*>(b1 + lane * 2);
    acc.x = fmaxf(acc.x + hs.x * sl + bb.x, 0.f);
    acc.y = fmaxf(acc.y + hs.y * sl + bb.y, 0.f);
    *reinterpret_cast<float2*>(Hagg + (size_t)gw * NH + lane * 2) = acc;
}

// ---------------- layer-2 gather (bf16 rows) + self + bias + log_softmax ----------------
__global__ void agg2_lsm(const int* __restrict__ offsets, const int2* __restrict__ erec,
                         const float* __restrict__ dinv, const __hip_bfloat16* __restrict__ H2,
                         const float* __restrict__ b2, float* __restrict__ out) {
    int node = (blockIdx.x * blockDim.x + threadIdx.x) >> 6;
    if (node >= NN) return;
    int lane = threadIdx.x & 63;
    int beg = offsets[node], end = offsets[node + 1];
    float acc = 0.f;
    for (int p = beg; p < end; ++p) {
        int2 r = erec[p];
        float w = __int_as_float(r.y);
        if (lane < NC) acc += __bfloat162float(H2[(size_t)r.x * NC + lane]) * w;
    }
    float di = dinv[node];
    float v = -INFINITY;
    if (lane < NC)
        v = acc + __bfloat162float(H2[(size_t)node * NC + lane]) * di * di + b2[lane];
    float m = v;
    #pragma unroll
    for (int off = 32; off; off >>= 1) m = fmaxf(m, __shfl_xor(m, off, 64));
    float ex = (lane < NC) ? expf(v - m) : 0.f;
    #pragma unroll
    for (int off = 32; off; off >>= 1) ex += __shfl_xor(ex, off, 64);
    float ls = logf(ex);
    if (lane < NC) out[(size_t)node * NC + lane] = v - m - ls;
}

extern "C" void kernel_launch(void* const* d_in, const int* in_sizes, int n_in,
                              void* d_out, int out_size, void* d_ws, size_t ws_size,
                              hipStream_t stream) {
    const float* x  = (const float*)d_in[0];
    const int*   ei = (const int*)d_in[1];    // [2, NE]: row 0 = src, row 1 = dst
    const float* W1 = (const float*)d_in[2];
    const float* b1 = (const float*)d_in[3];
    const float* W2 = (const float*)d_in[4];
    const float* b2 = (const float*)d_in[5];
    float* out = (float*)d_out;

    int*   counts  = (int*)d_ws;
    int*   offsets = counts + OFF_OFFSETS;
    int*   cursor  = counts + OFF_CURSOR;
    float* dinv    = (float*)(counts + OFF_DINV);
    int2*  erec    = (int2*)(counts + OFF_EREC);
    __hip_bfloat16* H    = (__hip_bfloat16*)(counts + OFF_H);
    float*          Hagg = (float*)(counts + OFF_HAGG);
    __hip_bfloat16* H2   = H;                  // reuse: H dead after agg1_gather

    // scan scratch inside H region (H not written until gemm1)
    int* blocksums = counts + OFF_H;           // [98]
    int* blockpref = counts + OFF_H + 128;     // [98]

    // 1. CSR build
    hipMemsetAsync(counts, 0, NN * sizeof(int), stream);
    count_kernel<<<(NE + 255) / 256, 256, 0, stream>>>(ei + NE, counts);
    dinv_kernel<<<(NN + 255) / 256, 256, 0, stream>>>(counts, dinv);
    scan_phase1<<<SCAN_NB, SCAN_TILE, 0, stream>>>(counts, blocksums);
    scan_phase2<<<1, 128, 0, stream>>>(blocksums, blockpref);
    scan_phase3<<<SCAN_NB, SCAN_TILE, 0, stream>>>(counts, blockpref, offsets, cursor);
    bucket_kernel<<<(NE + 255) / 256, 256, 0, stream>>>(ei, dinv, cursor, erec);

    // 2. H = bf16(x @ W1)
    {
        dim3 grid((NH + 63) / 64, (NN + 63) / 64);
        gemm_f32_bf16out<64, 64, 16, 4, 4><<<grid, 256, 0, stream>>>(x, W1, H, NN, NH, NF);
    }

    // 3. layer-1 gather (fused self-loop + bias + relu) -> Hagg (fp32)
    {
        long long threads = (long long)NN * 64;
        agg1_gather<<<(unsigned)((threads + 255) / 256), 256, 0, stream>>>(
            offsets, erec, dinv, H, b1, Hagg);
    }

    // 4. H2 = bf16(Hagg @ W2)
    {
        dim3 grid((NC + 63) / 64, (NN + 63) / 64);
        gemm_f32_bf16out<64, 64, 16, 4, 4><<<grid, 256, 0, stream>>>(Hagg, W2, H2, NN, NC, NH);
    }

    // 5. layer-2 gather + self + bias + log_softmax -> out
    {
        long long threads = (long long)NN * 64;
        agg2_lsm<<<(unsigned)((threads + 255) / 256), 256, 0, stream>>>(
            offsets, erec, dinv, H2, b2, out);
    }
}

// Round 5
// 698.637 us; speedup vs baseline: 1.1601x; 1.1601x over previous
//
#include <hip/hip_runtime.h>
#include <hip/hip_bf16.h>
#include <math.h>

#define NN 100000      // nodes
#define NE 1600000     // edges
#define NF 256         // input features
#define NH 128         // hidden
#define NC 40          // classes

// Workspace layout (4-byte units):
//   counts  [0,       100032)
//   offsets [100032,  200128)   (NN+1 used)
//   cursor  [200128,  300160)
//   dinv    [300160,  400192)
//   erec    [400192,  3600192)  (NE int2)
//   H       [3600192, 10000192) (bf16 NN*NH; scan scratch early; reused as H2 bf16 after agg1)
//   w1t     [10000192,10016576) (bf16 [128][256] transposed W1)
//   Hagg    [16400192,29200192) (NN*NH floats)
#define OFF_OFFSETS 100032
#define OFF_CURSOR  200128
#define OFF_DINV    300160
#define OFF_EREC    400192
#define OFF_H       3600192
#define OFF_W1T     10000192
#define OFF_HAGG    16400192

#define SCAN_TILE 1024
#define SCAN_NB   ((NN + SCAN_TILE - 1) / SCAN_TILE)   // 98

using f32x4  = __attribute__((ext_vector_type(4))) float;
using bf16x8 = __attribute__((ext_vector_type(8))) short;

// ---------------- CSR build ----------------
__global__ void count_kernel(const int* __restrict__ dst, int* __restrict__ count) {
    int t = blockIdx.x * blockDim.x + threadIdx.x;
    if (t < NE) atomicAdd(&count[dst[t]], 1);
}

__global__ void dinv_kernel(const int* __restrict__ count, float* __restrict__ dinv) {
    int t = blockIdx.x * blockDim.x + threadIdx.x;
    if (t < NN) dinv[t] = rsqrtf((float)count[t] + 1.0f);  // +1 self loop
}

// ---- hierarchical scan ----
__global__ void scan_phase1(const int* __restrict__ count, int* __restrict__ blocksums) {
    int b = blockIdx.x, t = threadIdx.x;
    int i = b * SCAN_TILE + t;
    int v = (i < NN) ? count[i] : 0;
    #pragma unroll
    for (int off = 32; off; off >>= 1) v += __shfl_xor(v, off, 64);
    __shared__ int ws[16];
    int lane = t & 63, wave = t >> 6;
    if (lane == 0) ws[wave] = v;
    __syncthreads();
    if (t == 0) {
        int s = 0;
        #pragma unroll
        for (int w = 0; w < SCAN_TILE / 64; ++w) s += ws[w];
        blocksums[b] = s;
    }
}

__global__ void scan_phase2(const int* __restrict__ blocksums, int* __restrict__ blockpref) {
    __shared__ int s[128];
    int t = threadIdx.x;
    int v = (t < SCAN_NB) ? blocksums[t] : 0;
    s[t] = v;
    __syncthreads();
    for (int off = 1; off < 128; off <<= 1) {
        int u = (t >= off) ? s[t - off] : 0;
        __syncthreads();
        s[t] += u;
        __syncthreads();
    }
    if (t < SCAN_NB) blockpref[t] = s[t] - v;
}

__global__ void scan_phase3(const int* __restrict__ count, const int* __restrict__ blockpref,
                            int* __restrict__ offsets, int* __restrict__ cursor) {
    int b = blockIdx.x, t = threadIdx.x;
    int i = b * SCAN_TILE + t;
    int v = (i < NN) ? count[i] : 0;
    int lane = t & 63, wave = t >> 6;
    int s = v;
    #pragma unroll
    for (int off = 1; off < 64; off <<= 1) {
        int u = __shfl_up(s, off, 64);
        if (lane >= off) s += u;
    }
    __shared__ int wsum[16];
    if (lane == 63) wsum[wave] = s;
    __syncthreads();
    if (t < 16) {
        int x = wsum[t];
        #pragma unroll
        for (int off = 1; off < 16; off <<= 1) {
            int u = __shfl_up(x, off, 64);
            if (t >= off) x += u;
        }
        wsum[t] = x;
    }
    __syncthreads();
    int excl = (s - v) + (wave ? wsum[wave - 1] : 0) + blockpref[b];
    if (i < NN) {
        offsets[i] = excl;
        cursor[i]  = excl;
        if (i == NN - 1) offsets[NN] = excl + v;
    }
}

__global__ void bucket_kernel(const int* __restrict__ ei, const float* __restrict__ dinv,
                              int* __restrict__ cursor, int2* __restrict__ erec) {
    int t = blockIdx.x * blockDim.x + threadIdx.x;
    if (t >= NE) return;
    int s = ei[t];
    int d = ei[NE + t];
    int pos = atomicAdd(&cursor[d], 1);
    float w = dinv[s] * dinv[d];
    erec[pos] = make_int2(s, __float_as_int(w));
}

// ---------------- W1 transpose+convert: w1t[n][k] = bf16(W1[k][n]) ----------------
__global__ void prep_w1t(const float* __restrict__ W1, __hip_bfloat16* __restrict__ W1t) {
    int i = blockIdx.x * 256 + threadIdx.x;
    if (i >= NH * NF) return;
    int n = i >> 8;       // /NF
    int k = i & (NF - 1);
    W1t[i] = __float2bfloat16(W1[(size_t)k * NH + n]);
}

__device__ inline short bfbits(float f) {
    __hip_bfloat16 h = __float2bfloat16(f);
    return __builtin_bit_cast(short, h);
}

// ---------------- layer-1 GEMM via MFMA: H = bf16(x @ W1) ----------------
// A = x fp32 [NN,256] staged raw, converted to bf16 per-fragment. B = w1t bf16 [128][256].
// 128x128 tile (full N), 4 waves as 2x2, each wave 4x4 frags of 16x16x32.
__global__ __launch_bounds__(256) void gemm1_mfma(const float* __restrict__ X,
                                                  const __hip_bfloat16* __restrict__ W1t,
                                                  __hip_bfloat16* __restrict__ H) {
    __shared__ __align__(16) float As[128 * 32];   // 16 KB, row-major [m][k]
    __shared__ __align__(16) short Bs[128 * 32];   // 8 KB,  row-major [n][k] (bf16 bits)

    const int tid  = threadIdx.x;
    const int wave = tid >> 6;
    const int lane = tid & 63;
    const int quad = lane >> 4;
    const int l16  = lane & 15;
    const int wy = wave >> 1, wx = wave & 1;
    const int m0 = blockIdx.x * 128;

    f32x4 acc[4][4] = {};

    for (int k0 = 0; k0 < NF; k0 += 32) {
        // stage A: 128 rows x 32 fp32 = 1024 x 16B chunks, 4 issues
        #pragma unroll
        for (int i = 0; i < 4; ++i) {
            int c   = i * 256 + tid;
            int row = c >> 3, cc = c & 7;
            int gr  = m0 + row; if (gr > NN - 1) gr = NN - 1;
            const float* gp = X + (size_t)gr * NF + k0 + cc * 4;
            __builtin_amdgcn_global_load_lds(
                (const __attribute__((address_space(1))) void*)gp,
                (__attribute__((address_space(3))) void*)&As[(i * 256 + wave * 64) * 4],
                16, 0, 0);
        }
        // stage B: 128 rows x 32 bf16 = 512 x 16B chunks, 2 issues
        #pragma unroll
        for (int i = 0; i < 2; ++i) {
            int c = i * 256 + tid;
            int n = c >> 2, cc = c & 3;
            const __hip_bfloat16* gp = W1t + (size_t)n * NF + k0 + cc * 8;
            __builtin_amdgcn_global_load_lds(
                (const __attribute__((address_space(1))) void*)gp,
                (__attribute__((address_space(3))) void*)&Bs[(i * 256 + wave * 64) * 8],
                16, 0, 0);
        }
        __syncthreads();

        bf16x8 a_frag[4], b_frag[4];
        #pragma unroll
        for (int mi = 0; mi < 4; ++mi) {
            const float* ap = &As[(wy * 64 + mi * 16 + l16) * 32 + quad * 8];
            f32x4 a0 = *(const f32x4*)ap;
            f32x4 a1 = *(const f32x4*)(ap + 4);
            bf16x8 af;
            af[0] = bfbits(a0.x); af[1] = bfbits(a0.y);
            af[2] = bfbits(a0.z); af[3] = bfbits(a0.w);
            af[4] = bfbits(a1.x); af[5] = bfbits(a1.y);
            af[6] = bfbits(a1.z); af[7] = bfbits(a1.w);
            a_frag[mi] = af;
        }
        #pragma unroll
        for (int ni = 0; ni < 4; ++ni) {
            const short* bp = &Bs[(wx * 64 + ni * 16 + l16) * 32 + quad * 8];
            b_frag[ni] = *(const bf16x8*)bp;
        }
        #pragma unroll
        for (int mi = 0; mi < 4; ++mi)
            #pragma unroll
            for (int ni = 0; ni < 4; ++ni)
                acc[mi][ni] = __builtin_amdgcn_mfma_f32_16x16x32_bf16(
                    a_frag[mi], b_frag[ni], acc[mi][ni], 0, 0, 0);
        __syncthreads();
    }

    // epilogue: C/D layout col=lane&15, row=quad*4+reg
    #pragma unroll
    for (int mi = 0; mi < 4; ++mi)
        #pragma unroll
        for (int v = 0; v < 4; ++v) {
            int r = m0 + wy * 64 + mi * 16 + quad * 4 + v;
            if (r < NN) {
                #pragma unroll
                for (int ni = 0; ni < 4; ++ni) {
                    int c = wx * 64 + ni * 16 + l16;
                    H[(size_t)r * NH + c] = __float2bfloat16(acc[mi][ni][v]);
                }
            }
        }
}

// ---------------- fp32 VALU GEMM (layer 2), bf16 output ----------------
template<int BM, int BN, int BK, int TM, int TN>
__global__ void gemm_f32_bf16out(const float* __restrict__ A, const float* __restrict__ B,
                                 __hip_bfloat16* __restrict__ C, int M, int N, int K) {
    constexpr int THREADS = (BM / TM) * (BN / TN);
    __shared__ float sA[BK][BM + 1];
    __shared__ float sB[BK][BN];
    const int tid  = threadIdx.x;
    const int tcol = tid % (BN / TN);
    const int trow = tid / (BN / TN);
    const int row0 = blockIdx.y * BM;
    const int col0 = blockIdx.x * BN;

    float acc[TM][TN];
    #pragma unroll
    for (int i = 0; i < TM; ++i)
        #pragma unroll
        for (int j = 0; j < TN; ++j) acc[i][j] = 0.f;

    for (int k0 = 0; k0 < K; k0 += BK) {
        #pragma unroll
        for (int idx = tid; idx < BM * BK; idx += THREADS) {
            int m = idx / BK, kk = idx % BK;
            int r = row0 + m;
            sA[kk][m] = (r < M) ? A[(size_t)r * K + k0 + kk] : 0.f;
        }
        #pragma unroll
        for (int idx = tid; idx < BK * BN; idx += THREADS) {
            int kk = idx / BN, n = idx % BN;
            int c = col0 + n;
            sB[kk][n] = (c < N) ? B[(size_t)(k0 + kk) * N + c] : 0.f;
        }
        __syncthreads();
        #pragma unroll
        for (int kk = 0; kk < BK; ++kk) {
            float a[TM], b[TN];
            #pragma unroll
            for (int i = 0; i < TM; ++i) a[i] = sA[kk][trow * TM + i];
            #pragma unroll
            for (int j = 0; j < TN; ++j) b[j] = sB[kk][tcol * TN + j];
            #pragma unroll
            for (int i = 0; i < TM; ++i)
                #pragma unroll
                for (int j = 0; j < TN; ++j) acc[i][j] += a[i] * b[j];
        }
        __syncthreads();
    }

    #pragma unroll
    for (int i = 0; i < TM; ++i) {
        int r = row0 + trow * TM + i;
        if (r >= M) continue;
        #pragma unroll
        for (int j = 0; j < TN; ++j) {
            int c = col0 + tcol * TN + j;
            if (c < N) C[(size_t)r * N + c] = __float2bfloat16(acc[i][j]);
        }
    }
}

// ---------------- layer-1 gather (bf16 rows): wave per dst node, fused self+bias+relu ----------------
__global__ void agg1_gather(const int* __restrict__ offsets, const int2* __restrict__ erec,
                            const float* __restrict__ dinv, const __hip_bfloat16* __restrict__ H,
                            const float* __restrict__ b1, float* __restrict__ Hagg) {
    int gw = (blockIdx.x * blockDim.x + threadIdx.x) >> 6;
    if (gw >= NN) return;
    int lane = threadIdx.x & 63;
    int beg = offsets[gw], end = offsets[gw + 1];
    const __hip_bfloat162* H2v = reinterpret_cast<const __hip_bfloat162*>(H);
    float2 acc = make_float2(0.f, 0.f);
    for (int p = beg; p < end; ++p) {
        int2 r = erec[p];
        float w = __int_as_float(r.y);
        float2 hv = __bfloat1622float2(H2v[(size_t)r.x * (NH / 2) + lane]);
        acc.x += hv.x * w;
        acc.y += hv.y * w;
    }
    float di = dinv[gw];
    float sl = di * di;
    float2 hs = __bfloat1622float2(H2v[(size_t)gw * (NH / 2) + lane]);
    float2 bb = *reinterpret_cast<const float2*>(b1 + lane * 2);
    acc.x = fmaxf(acc.x + hs.x * sl + bb.x, 0.f);
    acc.y = fmaxf(acc.y + hs.y * sl + bb.y, 0.f);
    *reinterpret_cast<float2*>(Hagg + (size_t)gw * NH + lane * 2) = acc;
}

// ---------------- layer-2 gather (bf16 rows) + self + bias + log_softmax ----------------
__global__ void agg2_lsm(const int* __restrict__ offsets, const int2* __restrict__ erec,
                         const float* __restrict__ dinv, const __hip_bfloat16* __restrict__ H2,
                         const float* __restrict__ b2, float* __restrict__ out) {
    int node = (blockIdx.x * blockDim.x + threadIdx.x) >> 6;
    if (node >= NN) return;
    int lane = threadIdx.x & 63;
    int beg = offsets[node], end = offsets[node + 1];
    float acc = 0.f;
    for (int p = beg; p < end; ++p) {
        int2 r = erec[p];
        float w = __int_as_float(r.y);
        if (lane < NC) acc += __bfloat162float(H2[(size_t)r.x * NC + lane]) * w;
    }
    float di = dinv[node];
    float v = -INFINITY;
    if (lane < NC)
        v = acc + __bfloat162float(H2[(size_t)node * NC + lane]) * di * di + b2[lane];
    float m = v;
    #pragma unroll
    for (int off = 32; off; off >>= 1) m = fmaxf(m, __shfl_xor(m, off, 64));
    float ex = (lane < NC) ? expf(v - m) : 0.f;
    #pragma unroll
    for (int off = 32; off; off >>= 1) ex += __shfl_xor(ex, off, 64);
    float ls = logf(ex);
    if (lane < NC) out[(size_t)node * NC + lane] = v - m - ls;
}

extern "C" void kernel_launch(void* const* d_in, const int* in_sizes, int n_in,
                              void* d_out, int out_size, void* d_ws, size_t ws_size,
                              hipStream_t stream) {
    const float* x  = (const float*)d_in[0];
    const int*   ei = (const int*)d_in[1];
    const float* W1 = (const float*)d_in[2];
    const float* b1 = (const float*)d_in[3];
    const float* W2 = (const float*)d_in[4];
    const float* b2 = (const float*)d_in[5];
    float* out = (float*)d_out;

    int*   counts  = (int*)d_ws;
    int*   offsets = counts + OFF_OFFSETS;
    int*   cursor  = counts + OFF_CURSOR;
    float* dinv    = (float*)(counts + OFF_DINV);
    int2*  erec    = (int2*)(counts + OFF_EREC);
    __hip_bfloat16* H    = (__hip_bfloat16*)(counts + OFF_H);
    __hip_bfloat16* W1t  = (__hip_bfloat16*)(counts + OFF_W1T);
    float*          Hagg = (float*)(counts + OFF_HAGG);
    __hip_bfloat16* H2   = H;                  // reuse after agg1

    int* blocksums = counts + OFF_H;           // scan scratch (before gemm1 writes H)
    int* blockpref = counts + OFF_H + 128;

    // 1. CSR build
    hipMemsetAsync(counts, 0, NN * sizeof(int), stream);
    count_kernel<<<(NE + 255) / 256, 256, 0, stream>>>(ei + NE, counts);
    dinv_kernel<<<(NN + 255) / 256, 256, 0, stream>>>(counts, dinv);
    scan_phase1<<<SCAN_NB, SCAN_TILE, 0, stream>>>(counts, blocksums);
    scan_phase2<<<1, 128, 0, stream>>>(blocksums, blockpref);
    scan_phase3<<<SCAN_NB, SCAN_TILE, 0, stream>>>(counts, blockpref, offsets, cursor);
    bucket_kernel<<<(NE + 255) / 256, 256, 0, stream>>>(ei, dinv, cursor, erec);

    // 2. W1 -> bf16 transposed; H = bf16(x @ W1) via MFMA
    prep_w1t<<<(NH * NF + 255) / 256, 256, 0, stream>>>(W1, W1t);
    gemm1_mfma<<<(NN + 127) / 128, 256, 0, stream>>>(x, W1t, H);

    // 3. layer-1 gather (fused self-loop + bias + relu) -> Hagg (fp32)
    {
        long long threads = (long long)NN * 64;
        agg1_gather<<<(unsigned)((threads + 255) / 256), 256, 0, stream>>>(
            offsets, erec, dinv, H, b1, Hagg);
    }

    // 4. H2 = bf16(Hagg @ W2)
    {
        dim3 grid((NC + 63) / 64, (NN + 63) / 64);
        gemm_f32_bf16out<64, 64, 16, 4, 4><<<grid, 256, 0, stream>>>(Hagg, W2, H2, NN, NC, NH);
    }

    // 5. layer-2 gather + self + bias + log_softmax -> out
    {
        long long threads = (long long)NN * 64;
        agg2_lsm<<<(unsigned)((threads + 255) / 256), 256, 0, stream>>>(
            offsets, erec, dinv, H2, b2, out);
    }
}

// Round 7
// 522.735 us; speedup vs baseline: 1.5505x; 1.3365x over previous
//
#include <hip/hip_runtime.h>
#include <hip/hip_bf16.h>
#include <math.h>

#define NN 100000      // nodes
#define NE 1600000     // edges
#define NF 256         // input features
#define NH 128         // hidden
#define NC 40          // classes
#define NCP 64         // padded classes (128-B rows)

// Workspace layout (4-byte units):
//   counts  [0,       100032)
//   offsets [100032,  200128)   (NN+1 used)
//   cursor  [200128,  300160)
//   dinv    [300160,  400192)
//   erec    [400192,  3600192)  (NE int2)
//   H       [3600192, 10000192) (bf16 NN*NH; scan scratch early; reused as padded H2 after agg1)
//   w1t     [10000192,10016576) (bf16 [128][256] transposed W1)
//   Hagg    [16400192,29200192) (NN*NH floats)
#define OFF_OFFSETS 100032
#define OFF_CURSOR  200128
#define OFF_DINV    300160
#define OFF_EREC    400192
#define OFF_H       3600192
#define OFF_W1T     10000192
#define OFF_HAGG    16400192

#define SCAN_TILE 1024
#define SCAN_NB   ((NN + SCAN_TILE - 1) / SCAN_TILE)   // 98

using f32x4  = __attribute__((ext_vector_type(4))) float;
using bf16x8 = __attribute__((ext_vector_type(8))) short;

// decode packed pair of bf16 (lo, hi) to fp32x2 — exact, pure bit ops
__device__ inline float2 cvt2(unsigned u) {
    float2 f;
    f.x = __uint_as_float(u << 16);
    f.y = __uint_as_float(u & 0xffff0000u);
    return f;
}

// ---------------- CSR build ----------------
__global__ void count_kernel(const int* __restrict__ dst, int* __restrict__ count) {
    int t = blockIdx.x * blockDim.x + threadIdx.x;
    if (t < NE) atomicAdd(&count[dst[t]], 1);
}

__global__ void dinv_kernel(const int* __restrict__ count, float* __restrict__ dinv) {
    int t = blockIdx.x * blockDim.x + threadIdx.x;
    if (t < NN) dinv[t] = rsqrtf((float)count[t] + 1.0f);  // +1 self loop
}

// ---- hierarchical scan ----
__global__ void scan_phase1(const int* __restrict__ count, int* __restrict__ blocksums) {
    int b = blockIdx.x, t = threadIdx.x;
    int i = b * SCAN_TILE + t;
    int v = (i < NN) ? count[i] : 0;
    #pragma unroll
    for (int off = 32; off; off >>= 1) v += __shfl_xor(v, off, 64);
    __shared__ int ws[16];
    int lane = t & 63, wave = t >> 6;
    if (lane == 0) ws[wave] = v;
    __syncthreads();
    if (t == 0) {
        int s = 0;
        #pragma unroll
        for (int w = 0; w < SCAN_TILE / 64; ++w) s += ws[w];
        blocksums[b] = s;
    }
}

__global__ void scan_phase2(const int* __restrict__ blocksums, int* __restrict__ blockpref) {
    __shared__ int s[128];
    int t = threadIdx.x;
    int v = (t < SCAN_NB) ? blocksums[t] : 0;
    s[t] = v;
    __syncthreads();
    for (int off = 1; off < 128; off <<= 1) {
        int u = (t >= off) ? s[t - off] : 0;
        __syncthreads();
        s[t] += u;
        __syncthreads();
    }
    if (t < SCAN_NB) blockpref[t] = s[t] - v;
}

__global__ void scan_phase3(const int* __restrict__ count, const int* __restrict__ blockpref,
                            int* __restrict__ offsets, int* __restrict__ cursor) {
    int b = blockIdx.x, t = threadIdx.x;
    int i = b * SCAN_TILE + t;
    int v = (i < NN) ? count[i] : 0;
    int lane = t & 63, wave = t >> 6;
    int s = v;
    #pragma unroll
    for (int off = 1; off < 64; off <<= 1) {
        int u = __shfl_up(s, off, 64);
        if (lane >= off) s += u;
    }
    __shared__ int wsum[16];
    if (lane == 63) wsum[wave] = s;
    __syncthreads();
    if (t < 16) {
        int x = wsum[t];
        #pragma unroll
        for (int off = 1; off < 16; off <<= 1) {
            int u = __shfl_up(x, off, 64);
            if (t >= off) x += u;
        }
        wsum[t] = x;
    }
    __syncthreads();
    int excl = (s - v) + (wave ? wsum[wave - 1] : 0) + blockpref[b];
    if (i < NN) {
        offsets[i] = excl;
        cursor[i]  = excl;
        if (i == NN - 1) offsets[NN] = excl + v;
    }
}

__global__ void bucket_kernel(const int* __restrict__ ei, const float* __restrict__ dinv,
                              int* __restrict__ cursor, int2* __restrict__ erec) {
    int t = blockIdx.x * blockDim.x + threadIdx.x;
    if (t >= NE) return;
    int s = ei[t];
    int d = ei[NE + t];
    int pos = atomicAdd(&cursor[d], 1);
    float w = dinv[s] * dinv[d];
    erec[pos] = make_int2(s, __float_as_int(w));
}

// ---------------- W1 transpose+convert ----------------
__global__ void prep_w1t(const float* __restrict__ W1, __hip_bfloat16* __restrict__ W1t) {
    int i = blockIdx.x * 256 + threadIdx.x;
    if (i >= NH * NF) return;
    int n = i >> 8;
    int k = i & (NF - 1);
    W1t[i] = __float2bfloat16(W1[(size_t)k * NH + n]);
}

__device__ inline short bfbits(float f) {
    __hip_bfloat16 h = __float2bfloat16(f);
    return *reinterpret_cast<short*>(&h);
}

// ---------------- layer-1 GEMM via MFMA: H = bf16(x @ W1) ----------------
__global__ __launch_bounds__(256) void gemm1_mfma(const float* __restrict__ X,
                                                  const __hip_bfloat16* __restrict__ W1t,
                                                  __hip_bfloat16* __restrict__ H) {
    __shared__ __align__(16) float As[128 * 32];
    __shared__ __align__(16) short Bs[128 * 32];

    const int tid  = threadIdx.x;
    const int wave = tid >> 6;
    const int lane = tid & 63;
    const int quad = lane >> 4;
    const int l16  = lane & 15;
    const int wy = wave >> 1, wx = wave & 1;
    const int m0 = blockIdx.x * 128;

    f32x4 acc[4][4] = {};

    for (int k0 = 0; k0 < NF; k0 += 32) {
        #pragma unroll
        for (int i = 0; i < 4; ++i) {
            int c   = i * 256 + tid;
            int row = c >> 3, cc = c & 7;
            int gr  = m0 + row; if (gr > NN - 1) gr = NN - 1;
            const float* gp = X + (size_t)gr * NF + k0 + cc * 4;
            __builtin_amdgcn_global_load_lds(
                (const __attribute__((address_space(1))) void*)gp,
                (__attribute__((address_space(3))) void*)&As[(i * 256 + wave * 64) * 4],
                16, 0, 0);
        }
        #pragma unroll
        for (int i = 0; i < 2; ++i) {
            int c = i * 256 + tid;
            int n = c >> 2, cc = c & 3;
            const __hip_bfloat16* gp = W1t + (size_t)n * NF + k0 + cc * 8;
            __builtin_amdgcn_global_load_lds(
                (const __attribute__((address_space(1))) void*)gp,
                (__attribute__((address_space(3))) void*)&Bs[(i * 256 + wave * 64) * 8],
                16, 0, 0);
        }
        __syncthreads();

        bf16x8 a_frag[4], b_frag[4];
        #pragma unroll
        for (int mi = 0; mi < 4; ++mi) {
            const float* ap = &As[(wy * 64 + mi * 16 + l16) * 32 + quad * 8];
            f32x4 a0 = *(const f32x4*)ap;
            f32x4 a1 = *(const f32x4*)(ap + 4);
            bf16x8 af;
            af[0] = bfbits(a0.x); af[1] = bfbits(a0.y);
            af[2] = bfbits(a0.z); af[3] = bfbits(a0.w);
            af[4] = bfbits(a1.x); af[5] = bfbits(a1.y);
            af[6] = bfbits(a1.z); af[7] = bfbits(a1.w);
            a_frag[mi] = af;
        }
        #pragma unroll
        for (int ni = 0; ni < 4; ++ni) {
            const short* bp = &Bs[(wx * 64 + ni * 16 + l16) * 32 + quad * 8];
            b_frag[ni] = *(const bf16x8*)bp;
        }
        #pragma unroll
        for (int mi = 0; mi < 4; ++mi)
            #pragma unroll
            for (int ni = 0; ni < 4; ++ni)
                acc[mi][ni] = __builtin_amdgcn_mfma_f32_16x16x32_bf16(
                    a_frag[mi], b_frag[ni], acc[mi][ni], 0, 0, 0);
        __syncthreads();
    }

    #pragma unroll
    for (int mi = 0; mi < 4; ++mi)
        #pragma unroll
        for (int v = 0; v < 4; ++v) {
            int r = m0 + wy * 64 + mi * 16 + quad * 4 + v;
            if (r < NN) {
                #pragma unroll
                for (int ni = 0; ni < 4; ++ni) {
                    int c = wx * 64 + ni * 16 + l16;
                    H[(size_t)r * NH + c] = __float2bfloat16(acc[mi][ni][v]);
                }
            }
        }
}

// ---------------- layer-2 GEMM (fp32 VALU), padded 64-wide bf16 output ----------------
// C[M,64] = A[M,128] @ Bpad[128,64] where Bpad[:,40:64] = 0
__global__ void gemm2_pad(const float* __restrict__ A, const float* __restrict__ B,
                          __hip_bfloat16* __restrict__ C, int M) {
    constexpr int BM = 64, BN = 64, BK = 16, TM = 4, TN = 4;
    constexpr int THREADS = (BM / TM) * (BN / TN);
    __shared__ float sA[BK][BM + 1];
    __shared__ float sB[BK][BN];
    const int tid  = threadIdx.x;
    const int tcol = tid % (BN / TN);
    const int trow = tid / (BN / TN);
    const int row0 = blockIdx.x * BM;

    float acc[TM][TN];
    #pragma unroll
    for (int i = 0; i < TM; ++i)
        #pragma unroll
        for (int j = 0; j < TN; ++j) acc[i][j] = 0.f;

    for (int k0 = 0; k0 < NH; k0 += BK) {
        #pragma unroll
        for (int idx = tid; idx < BM * BK; idx += THREADS) {
            int m = idx / BK, kk = idx % BK;
            int r = row0 + m;
            sA[kk][m] = (r < M) ? A[(size_t)r * NH + k0 + kk] : 0.f;
        }
        #pragma unroll
        for (int idx = tid; idx < BK * BN; idx += THREADS) {
            int kk = idx / BN, c = idx % BN;
            sB[kk][c] = (c < NC) ? B[(size_t)(k0 + kk) * NC + c] : 0.f;
        }
        __syncthreads();
        #pragma unroll
        for (int kk = 0; kk < BK; ++kk) {
            float a[TM], b[TN];
            #pragma unroll
            for (int i = 0; i < TM; ++i) a[i] = sA[kk][trow * TM + i];
            #pragma unroll
            for (int j = 0; j < TN; ++j) b[j] = sB[kk][tcol * TN + j];
            #pragma unroll
            for (int i = 0; i < TM; ++i)
                #pragma unroll
                for (int j = 0; j < TN; ++j) acc[i][j] += a[i] * b[j];
        }
        __syncthreads();
    }

    #pragma unroll
    for (int i = 0; i < TM; ++i) {
        int r = row0 + trow * TM + i;
        if (r >= M) continue;
        #pragma unroll
        for (int j = 0; j < TN; ++j) {
            int c = tcol * TN + j;
            C[(size_t)r * NCP + c] = __float2bfloat16(acc[i][j]);
        }
    }
}

// ---------------- layer-1 gather: wave per node, 4 edge-groups x 16 lanes x 16B ----------------
__global__ void agg1_gather(const int* __restrict__ offsets, const int2* __restrict__ erec,
                            const float* __restrict__ dinv, const __hip_bfloat16* __restrict__ H,
                            const float* __restrict__ b1, float* __restrict__ Hagg) {
    int node = (blockIdx.x * blockDim.x + threadIdx.x) >> 6;
    if (node >= NN) return;
    int lane = threadIdx.x & 63;
    int grp = lane >> 4, l16 = lane & 15;
    int beg = offsets[node], end = offsets[node + 1];
    const uint4* Hv = reinterpret_cast<const uint4*>(H);   // 8 bf16 per uint4, 16 per row
    float acc[8] = {};
    for (int p = beg + grp; p < end; p += 4) {
        int2 r = erec[p];
        float w = __int_as_float(r.y);
        uint4 hv = Hv[(size_t)r.x * 16 + l16];
        float2 f0 = cvt2(hv.x), f1 = cvt2(hv.y), f2 = cvt2(hv.z), f3 = cvt2(hv.w);
        acc[0] += f0.x * w; acc[1] += f0.y * w;
        acc[2] += f1.x * w; acc[3] += f1.y * w;
        acc[4] += f2.x * w; acc[5] += f2.y * w;
        acc[6] += f3.x * w; acc[7] += f3.y * w;
    }
    #pragma unroll
    for (int k = 0; k < 8; ++k) {
        acc[k] += __shfl_xor(acc[k], 16, 64);
        acc[k] += __shfl_xor(acc[k], 32, 64);
    }
    if (lane < 16) {
        float di = dinv[node];
        float sl = di * di;
        uint4 hs = Hv[(size_t)node * 16 + l16];
        float2 s0 = cvt2(hs.x), s1 = cvt2(hs.y), s2 = cvt2(hs.z), s3 = cvt2(hs.w);
        const float4* bb = reinterpret_cast<const float4*>(b1 + l16 * 8);
        float4 ba = bb[0], bc = bb[1];
        float4 o0, o1;
        o0.x = fmaxf(acc[0] + s0.x * sl + ba.x, 0.f);
        o0.y = fmaxf(acc[1] + s0.y * sl + ba.y, 0.f);
        o0.z = fmaxf(acc[2] + s1.x * sl + ba.z, 0.f);
        o0.w = fmaxf(acc[3] + s1.y * sl + ba.w, 0.f);
        o1.x = fmaxf(acc[4] + s2.x * sl + bc.x, 0.f);
        o1.y = fmaxf(acc[5] + s2.y * sl + bc.y, 0.f);
        o1.z = fmaxf(acc[6] + s3.x * sl + bc.z, 0.f);
        o1.w = fmaxf(acc[7] + s3.y * sl + bc.w, 0.f);
        float4* op = reinterpret_cast<float4*>(Hagg + (size_t)node * NH + l16 * 8);
        op[0] = o0;
        op[1] = o1;
    }
}

// ---------------- layer-2 gather + self + bias + log_softmax (padded H2) ----------------
__global__ void agg2_lsm(const int* __restrict__ offsets, const int2* __restrict__ erec,
                         const float* __restrict__ dinv, const __hip_bfloat16* __restrict__ H2p,
                         const float* __restrict__ b2, float* __restrict__ out) {
    int node = (blockIdx.x * blockDim.x + threadIdx.x) >> 6;
    if (node >= NN) return;
    int lane = threadIdx.x & 63;
    int grp = lane >> 4, l16 = lane & 15;
    int beg = offsets[node], end = offsets[node + 1];
    const uint2* Hv = reinterpret_cast<const uint2*>(H2p);  // 4 bf16 per uint2, 16 per row
    float acc[4] = {};
    for (int p = beg + grp; p < end; p += 4) {
        int2 r = erec[p];
        float w = __int_as_float(r.y);
        uint2 hv = Hv[(size_t)r.x * 16 + l16];
        float2 f0 = cvt2(hv.x), f1 = cvt2(hv.y);
        acc[0] += f0.x * w; acc[1] += f0.y * w;
        acc[2] += f1.x * w; acc[3] += f1.y * w;
    }
    #pragma unroll
    for (int k = 0; k < 4; ++k) {
        acc[k] += __shfl_xor(acc[k], 16, 64);
        acc[k] += __shfl_xor(acc[k], 32, 64);
    }
    float di = dinv[node];
    float sl = di * di;
    uint2 hs = Hv[(size_t)node * 16 + l16];
    float2 s0 = cvt2(hs.x), s1 = cvt2(hs.y);
    float v[4];
    bool valid = (l16 < 10);   // classes l16*4..l16*4+3 < 40
    if (valid) {
        float4 bb = *reinterpret_cast<const float4*>(b2 + l16 * 4);
        v[0] = acc[0] + s0.x * sl + bb.x;
        v[1] = acc[1] + s0.y * sl + bb.y;
        v[2] = acc[2] + s1.x * sl + bb.z;
        v[3] = acc[3] + s1.y * sl + bb.w;
    } else {
        v[0] = v[1] = v[2] = v[3] = -INFINITY;
    }
    float m = fmaxf(fmaxf(v[0], v[1]), fmaxf(v[2], v[3]));
    #pragma unroll
    for (int off = 8; off; off >>= 1) m = fmaxf(m, __shfl_xor(m, off, 64));
    float ex = expf(v[0] - m) + expf(v[1] - m) + expf(v[2] - m) + expf(v[3] - m);
    #pragma unroll
    for (int off = 8; off; off >>= 1) ex += __shfl_xor(ex, off, 64);
    float ls = logf(ex);
    if (lane < 16 && valid) {
        float4 o;
        o.x = v[0] - m - ls; o.y = v[1] - m - ls;
        o.z = v[2] - m - ls; o.w = v[3] - m - ls;
        *reinterpret_cast<float4*>(out + (size_t)node * NC + l16 * 4) = o;
    }
}

extern "C" void kernel_launch(void* const* d_in, const int* in_sizes, int n_in,
                              void* d_out, int out_size, void* d_ws, size_t ws_size,
                              hipStream_t stream) {
    const float* x  = (const float*)d_in[0];
    const int*   ei = (const int*)d_in[1];
    const float* W1 = (const float*)d_in[2];
    const float* b1 = (const float*)d_in[3];
    const float* W2 = (const float*)d_in[4];
    const float* b2 = (const float*)d_in[5];
    float* out = (float*)d_out;

    int*   counts  = (int*)d_ws;
    int*   offsets = counts + OFF_OFFSETS;
    int*   cursor  = counts + OFF_CURSOR;
    float* dinv    = (float*)(counts + OFF_DINV);
    int2*  erec    = (int2*)(counts + OFF_EREC);
    __hip_bfloat16* H    = (__hip_bfloat16*)(counts + OFF_H);
    __hip_bfloat16* W1t  = (__hip_bfloat16*)(counts + OFF_W1T);
    float*          Hagg = (float*)(counts + OFF_HAGG);
    __hip_bfloat16* H2p  = H;                  // padded [NN][64] bf16, reuses H after agg1

    int* blocksums = counts + OFF_H;           // scan scratch (before gemm1 writes H)
    int* blockpref = counts + OFF_H + 128;

    // 1. CSR build
    (void)hipMemsetAsync(counts, 0, NN * sizeof(int), stream);
    count_kernel<<<(NE + 255) / 256, 256, 0, stream>>>(ei + NE, counts);
    dinv_kernel<<<(NN + 255) / 256, 256, 0, stream>>>(counts, dinv);
    scan_phase1<<<SCAN_NB, SCAN_TILE, 0, stream>>>(counts, blocksums);
    scan_phase2<<<1, 128, 0, stream>>>(blocksums, blockpref);
    scan_phase3<<<SCAN_NB, SCAN_TILE, 0, stream>>>(counts, blockpref, offsets, cursor);
    bucket_kernel<<<(NE + 255) / 256, 256, 0, stream>>>(ei, dinv, cursor, erec);

    // 2. W1 -> bf16 transposed; H = bf16(x @ W1) via MFMA
    prep_w1t<<<(NH * NF + 255) / 256, 256, 0, stream>>>(W1, W1t);
    gemm1_mfma<<<(NN + 127) / 128, 256, 0, stream>>>(x, W1t, H);

    // 3. layer-1 gather (fused self-loop + bias + relu) -> Hagg (fp32)
    {
        long long threads = (long long)NN * 64;
        agg1_gather<<<(unsigned)((threads + 255) / 256), 256, 0, stream>>>(
            offsets, erec, dinv, H, b1, Hagg);
    }

    // 4. H2p = bf16(Hagg @ W2) padded to 64 cols (pad = 0)
    gemm2_pad<<<(NN + 63) / 64, 256, 0, stream>>>(Hagg, W2, H2p, NN);

    // 5. layer-2 gather + self + bias + log_softmax -> out
    {
        long long threads = (long long)NN * 64;
        agg2_lsm<<<(unsigned)((threads + 255) / 256), 256, 0, stream>>>(
            offsets, erec, dinv, H2p, b2, out);
    }
}

// Round 8
// 483.599 us; speedup vs baseline: 1.6760x; 1.0809x over previous
//
#include <hip/hip_runtime.h>
#include <hip/hip_bf16.h>
#include <math.h>

#define NN 100000      // nodes
#define NE 1600000     // edges
#define NF 256         // input features
#define NH 128         // hidden
#define NC 40          // classes
#define NCP 64         // padded classes (128-B rows)

// Workspace layout (4-byte units):
#define OFF_OFFSETS 100032
#define OFF_CURSOR  200128
#define OFF_DINV    300160
#define OFF_EREC    400192
#define OFF_H       3600192
#define OFF_W1T     10000192
#define OFF_HAGG    16400192

#define SCAN_TILE 1024
#define SCAN_NB   ((NN + SCAN_TILE - 1) / SCAN_TILE)   // 98

#define GEMM1_NB  ((NN + 127) / 128)    // 782
#define BUCKET_NB ((NE + 255) / 256)    // 6250

using f32x4  = __attribute__((ext_vector_type(4))) float;
using bf16x8 = __attribute__((ext_vector_type(8))) short;

// decode packed pair of bf16 (lo, hi) to fp32x2 — exact, pure bit ops
__device__ inline float2 cvt2(unsigned u) {
    float2 f;
    f.x = __uint_as_float(u << 16);
    f.y = __uint_as_float(u & 0xffff0000u);
    return f;
}

__device__ inline short bfbits(float f) {
    __hip_bfloat16 h = __float2bfloat16(f);
    return *reinterpret_cast<short*>(&h);
}

// ---------------- count + W1 transpose/convert (fused, independent work) ----------------
__global__ void count_prep(const int* __restrict__ dst, int* __restrict__ count,
                           const float* __restrict__ W1, __hip_bfloat16* __restrict__ W1t) {
    int t = blockIdx.x * blockDim.x + threadIdx.x;
    if (t < NE) atomicAdd(&count[dst[t]], 1);
    if (t < NH * NF) {
        int n = t >> 8;
        int k = t & (NF - 1);
        W1t[t] = __float2bfloat16(W1[(size_t)k * NH + n]);
    }
}

// ---- hierarchical scan ----
__global__ void scan_phase1(const int* __restrict__ count, int* __restrict__ blocksums) {
    int b = blockIdx.x, t = threadIdx.x;
    int i = b * SCAN_TILE + t;
    int v = (i < NN) ? count[i] : 0;
    #pragma unroll
    for (int off = 32; off; off >>= 1) v += __shfl_xor(v, off, 64);
    __shared__ int ws[16];
    int lane = t & 63, wave = t >> 6;
    if (lane == 0) ws[wave] = v;
    __syncthreads();
    if (t == 0) {
        int s = 0;
        #pragma unroll
        for (int w = 0; w < SCAN_TILE / 64; ++w) s += ws[w];
        blocksums[b] = s;
    }
}

__global__ void scan_phase2(const int* __restrict__ blocksums, int* __restrict__ blockpref) {
    __shared__ int s[128];
    int t = threadIdx.x;
    int v = (t < SCAN_NB) ? blocksums[t] : 0;
    s[t] = v;
    __syncthreads();
    for (int off = 1; off < 128; off <<= 1) {
        int u = (t >= off) ? s[t - off] : 0;
        __syncthreads();
        s[t] += u;
        __syncthreads();
    }
    if (t < SCAN_NB) blockpref[t] = s[t] - v;
}

// phase 3 also produces dinv (count already in hand)
__global__ void scan_phase3(const int* __restrict__ count, const int* __restrict__ blockpref,
                            int* __restrict__ offsets, int* __restrict__ cursor,
                            float* __restrict__ dinv) {
    int b = blockIdx.x, t = threadIdx.x;
    int i = b * SCAN_TILE + t;
    int v = (i < NN) ? count[i] : 0;
    int lane = t & 63, wave = t >> 6;
    int s = v;
    #pragma unroll
    for (int off = 1; off < 64; off <<= 1) {
        int u = __shfl_up(s, off, 64);
        if (lane >= off) s += u;
    }
    __shared__ int wsum[16];
    if (lane == 63) wsum[wave] = s;
    __syncthreads();
    if (t < 16) {
        int x = wsum[t];
        #pragma unroll
        for (int off = 1; off < 16; off <<= 1) {
            int u = __shfl_up(x, off, 64);
            if (t >= off) x += u;
        }
        wsum[t] = x;
    }
    __syncthreads();
    int excl = (s - v) + (wave ? wsum[wave - 1] : 0) + blockpref[b];
    if (i < NN) {
        offsets[i] = excl;
        cursor[i]  = excl;
        dinv[i]    = rsqrtf((float)v + 1.0f);   // +1 self loop
        if (i == NN - 1) offsets[NN] = excl + v;
    }
}

// ---------------- FUSED: bucket scatter (blocks >= GEMM1_NB) + layer-1 MFMA GEMM ----------------
__global__ __launch_bounds__(256, 4) void bucket_gemm1(
        const int* __restrict__ ei, const float* __restrict__ dinv,
        int* __restrict__ cursor, int2* __restrict__ erec,
        const float* __restrict__ X, const __hip_bfloat16* __restrict__ W1t,
        __hip_bfloat16* __restrict__ H) {
    if (blockIdx.x >= GEMM1_NB) {
        // ---- bucket path ----
        int t = (blockIdx.x - GEMM1_NB) * 256 + threadIdx.x;
        if (t >= NE) return;
        int s = ei[t];
        int d = ei[NE + t];
        int pos = atomicAdd(&cursor[d], 1);
        float w = dinv[s] * dinv[d];
        erec[pos] = make_int2(s, __float_as_int(w));
        return;
    }
    // ---- gemm1 path: H = bf16(x @ W1), 128x128 tile ----
    __shared__ __align__(16) float As[128 * 32];
    __shared__ __align__(16) short Bs[128 * 32];

    const int tid  = threadIdx.x;
    const int wave = tid >> 6;
    const int lane = tid & 63;
    const int quad = lane >> 4;
    const int l16  = lane & 15;
    const int wy = wave >> 1, wx = wave & 1;
    const int m0 = blockIdx.x * 128;

    f32x4 acc[4][4] = {};

    for (int k0 = 0; k0 < NF; k0 += 32) {
        #pragma unroll
        for (int i = 0; i < 4; ++i) {
            int c   = i * 256 + tid;
            int row = c >> 3, cc = c & 7;
            int gr  = m0 + row; if (gr > NN - 1) gr = NN - 1;
            const float* gp = X + (size_t)gr * NF + k0 + cc * 4;
            __builtin_amdgcn_global_load_lds(
                (const __attribute__((address_space(1))) void*)gp,
                (__attribute__((address_space(3))) void*)&As[(i * 256 + wave * 64) * 4],
                16, 0, 0);
        }
        #pragma unroll
        for (int i = 0; i < 2; ++i) {
            int c = i * 256 + tid;
            int n = c >> 2, cc = c & 3;
            const __hip_bfloat16* gp = W1t + (size_t)n * NF + k0 + cc * 8;
            __builtin_amdgcn_global_load_lds(
                (const __attribute__((address_space(1))) void*)gp,
                (__attribute__((address_space(3))) void*)&Bs[(i * 256 + wave * 64) * 8],
                16, 0, 0);
        }
        __syncthreads();

        bf16x8 a_frag[4], b_frag[4];
        #pragma unroll
        for (int mi = 0; mi < 4; ++mi) {
            const float* ap = &As[(wy * 64 + mi * 16 + l16) * 32 + quad * 8];
            f32x4 a0 = *(const f32x4*)ap;
            f32x4 a1 = *(const f32x4*)(ap + 4);
            bf16x8 af;
            af[0] = bfbits(a0.x); af[1] = bfbits(a0.y);
            af[2] = bfbits(a0.z); af[3] = bfbits(a0.w);
            af[4] = bfbits(a1.x); af[5] = bfbits(a1.y);
            af[6] = bfbits(a1.z); af[7] = bfbits(a1.w);
            a_frag[mi] = af;
        }
        #pragma unroll
        for (int ni = 0; ni < 4; ++ni) {
            const short* bp = &Bs[(wx * 64 + ni * 16 + l16) * 32 + quad * 8];
            b_frag[ni] = *(const bf16x8*)bp;
        }
        #pragma unroll
        for (int mi = 0; mi < 4; ++mi)
            #pragma unroll
            for (int ni = 0; ni < 4; ++ni)
                acc[mi][ni] = __builtin_amdgcn_mfma_f32_16x16x32_bf16(
                    a_frag[mi], b_frag[ni], acc[mi][ni], 0, 0, 0);
        __syncthreads();
    }

    #pragma unroll
    for (int mi = 0; mi < 4; ++mi)
        #pragma unroll
        for (int v = 0; v < 4; ++v) {
            int r = m0 + wy * 64 + mi * 16 + quad * 4 + v;
            if (r < NN) {
                #pragma unroll
                for (int ni = 0; ni < 4; ++ni) {
                    int c = wx * 64 + ni * 16 + l16;
                    H[(size_t)r * NH + c] = __float2bfloat16(acc[mi][ni][v]);
                }
            }
        }
}

// ---------------- layer-2 GEMM (fp32 VALU), padded 64-wide bf16 output ----------------
__global__ void gemm2_pad(const float* __restrict__ A, const float* __restrict__ B,
                          __hip_bfloat16* __restrict__ C, int M) {
    constexpr int BM = 64, BN = 64, BK = 16, TM = 4, TN = 4;
    constexpr int THREADS = (BM / TM) * (BN / TN);
    __shared__ float sA[BK][BM + 1];
    __shared__ float sB[BK][BN];
    const int tid  = threadIdx.x;
    const int tcol = tid % (BN / TN);
    const int trow = tid / (BN / TN);
    const int row0 = blockIdx.x * BM;

    float acc[TM][TN];
    #pragma unroll
    for (int i = 0; i < TM; ++i)
        #pragma unroll
        for (int j = 0; j < TN; ++j) acc[i][j] = 0.f;

    for (int k0 = 0; k0 < NH; k0 += BK) {
        #pragma unroll
        for (int idx = tid; idx < BM * BK; idx += THREADS) {
            int m = idx / BK, kk = idx % BK;
            int r = row0 + m;
            sA[kk][m] = (r < M) ? A[(size_t)r * NH + k0 + kk] : 0.f;
        }
        #pragma unroll
        for (int idx = tid; idx < BK * BN; idx += THREADS) {
            int kk = idx / BN, c = idx % BN;
            sB[kk][c] = (c < NC) ? B[(size_t)(k0 + kk) * NC + c] : 0.f;
        }
        __syncthreads();
        #pragma unroll
        for (int kk = 0; kk < BK; ++kk) {
            float a[TM], b[TN];
            #pragma unroll
            for (int i = 0; i < TM; ++i) a[i] = sA[kk][trow * TM + i];
            #pragma unroll
            for (int j = 0; j < TN; ++j) b[j] = sB[kk][tcol * TN + j];
            #pragma unroll
            for (int i = 0; i < TM; ++i)
                #pragma unroll
                for (int j = 0; j < TN; ++j) acc[i][j] += a[i] * b[j];
        }
        __syncthreads();
    }

    #pragma unroll
    for (int i = 0; i < TM; ++i) {
        int r = row0 + trow * TM + i;
        if (r >= M) continue;
        #pragma unroll
        for (int j = 0; j < TN; ++j) {
            int c = tcol * TN + j;
            C[(size_t)r * NCP + c] = __float2bfloat16(acc[i][j]);
        }
    }
}

// ---------------- layer-1 gather: wave per node, 4 groups x 16 lanes, 2 edges in flight/group ----------------
__global__ void agg1_gather(const int* __restrict__ offsets, const int2* __restrict__ erec,
                            const float* __restrict__ dinv, const __hip_bfloat16* __restrict__ H,
                            const float* __restrict__ b1, float* __restrict__ Hagg) {
    int node = (blockIdx.x * blockDim.x + threadIdx.x) >> 6;
    if (node >= NN) return;
    int lane = threadIdx.x & 63;
    int grp = lane >> 4, l16 = lane & 15;
    int beg = offsets[node], end = offsets[node + 1];
    const uint4* Hv = reinterpret_cast<const uint4*>(H);   // 8 bf16 per uint4, 16 per row
    float acc[8] = {};
    int p = beg + grp;
    for (; p + 4 < end; p += 8) {
        int2 r1 = erec[p];
        int2 r2 = erec[p + 4];
        float w1 = __int_as_float(r1.y);
        float w2 = __int_as_float(r2.y);
        uint4 h1 = Hv[(size_t)r1.x * 16 + l16];
        uint4 h2 = Hv[(size_t)r2.x * 16 + l16];
        float2 a0 = cvt2(h1.x), a1 = cvt2(h1.y), a2 = cvt2(h1.z), a3 = cvt2(h1.w);
        acc[0] += a0.x * w1; acc[1] += a0.y * w1;
        acc[2] += a1.x * w1; acc[3] += a1.y * w1;
        acc[4] += a2.x * w1; acc[5] += a2.y * w1;
        acc[6] += a3.x * w1; acc[7] += a3.y * w1;
        float2 c0 = cvt2(h2.x), c1 = cvt2(h2.y), c2 = cvt2(h2.z), c3 = cvt2(h2.w);
        acc[0] += c0.x * w2; acc[1] += c0.y * w2;
        acc[2] += c1.x * w2; acc[3] += c1.y * w2;
        acc[4] += c2.x * w2; acc[5] += c2.y * w2;
        acc[6] += c3.x * w2; acc[7] += c3.y * w2;
    }
    if (p < end) {
        int2 r = erec[p];
        float w = __int_as_float(r.y);
        uint4 hv = Hv[(size_t)r.x * 16 + l16];
        float2 f0 = cvt2(hv.x), f1 = cvt2(hv.y), f2 = cvt2(hv.z), f3 = cvt2(hv.w);
        acc[0] += f0.x * w; acc[1] += f0.y * w;
        acc[2] += f1.x * w; acc[3] += f1.y * w;
        acc[4] += f2.x * w; acc[5] += f2.y * w;
        acc[6] += f3.x * w; acc[7] += f3.y * w;
    }
    #pragma unroll
    for (int k = 0; k < 8; ++k) {
        acc[k] += __shfl_xor(acc[k], 16, 64);
        acc[k] += __shfl_xor(acc[k], 32, 64);
    }
    if (lane < 16) {
        float di = dinv[node];
        float sl = di * di;
        uint4 hs = Hv[(size_t)node * 16 + l16];
        float2 s0 = cvt2(hs.x), s1 = cvt2(hs.y), s2 = cvt2(hs.z), s3 = cvt2(hs.w);
        const float4* bb = reinterpret_cast<const float4*>(b1 + l16 * 8);
        float4 ba = bb[0], bc = bb[1];
        float4 o0, o1;
        o0.x = fmaxf(acc[0] + s0.x * sl + ba.x, 0.f);
        o0.y = fmaxf(acc[1] + s0.y * sl + ba.y, 0.f);
        o0.z = fmaxf(acc[2] + s1.x * sl + ba.z, 0.f);
        o0.w = fmaxf(acc[3] + s1.y * sl + ba.w, 0.f);
        o1.x = fmaxf(acc[4] + s2.x * sl + bc.x, 0.f);
        o1.y = fmaxf(acc[5] + s2.y * sl + bc.y, 0.f);
        o1.z = fmaxf(acc[6] + s3.x * sl + bc.z, 0.f);
        o1.w = fmaxf(acc[7] + s3.y * sl + bc.w, 0.f);
        float4* op = reinterpret_cast<float4*>(Hagg + (size_t)node * NH + l16 * 8);
        op[0] = o0;
        op[1] = o1;
    }
}

// ---------------- layer-2 gather + self + bias + log_softmax (padded H2) ----------------
__global__ void agg2_lsm(const int* __restrict__ offsets, const int2* __restrict__ erec,
                         const float* __restrict__ dinv, const __hip_bfloat16* __restrict__ H2p,
                         const float* __restrict__ b2, float* __restrict__ out) {
    int node = (blockIdx.x * blockDim.x + threadIdx.x) >> 6;
    if (node >= NN) return;
    int lane = threadIdx.x & 63;
    int grp = lane >> 4, l16 = lane & 15;
    int beg = offsets[node], end = offsets[node + 1];
    const uint2* Hv = reinterpret_cast<const uint2*>(H2p);  // 4 bf16 per uint2, 16 per row
    float acc[4] = {};
    int p = beg + grp;
    for (; p + 4 < end; p += 8) {
        int2 r1 = erec[p];
        int2 r2 = erec[p + 4];
        float w1 = __int_as_float(r1.y);
        float w2 = __int_as_float(r2.y);
        uint2 h1 = Hv[(size_t)r1.x * 16 + l16];
        uint2 h2 = Hv[(size_t)r2.x * 16 + l16];
        float2 a0 = cvt2(h1.x), a1 = cvt2(h1.y);
        acc[0] += a0.x * w1; acc[1] += a0.y * w1;
        acc[2] += a1.x * w1; acc[3] += a1.y * w1;
        float2 c0 = cvt2(h2.x), c1 = cvt2(h2.y);
        acc[0] += c0.x * w2; acc[1] += c0.y * w2;
        acc[2] += c1.x * w2; acc[3] += c1.y * w2;
    }
    if (p < end) {
        int2 r = erec[p];
        float w = __int_as_float(r.y);
        uint2 hv = Hv[(size_t)r.x * 16 + l16];
        float2 f0 = cvt2(hv.x), f1 = cvt2(hv.y);
        acc[0] += f0.x * w; acc[1] += f0.y * w;
        acc[2] += f1.x * w; acc[3] += f1.y * w;
    }
    #pragma unroll
    for (int k = 0; k < 4; ++k) {
        acc[k] += __shfl_xor(acc[k], 16, 64);
        acc[k] += __shfl_xor(acc[k], 32, 64);
    }
    float di = dinv[node];
    float sl = di * di;
    uint2 hs = Hv[(size_t)node * 16 + l16];
    float2 s0 = cvt2(hs.x), s1 = cvt2(hs.y);
    float v[4];
    bool valid = (l16 < 10);   // classes l16*4..l16*4+3 < 40
    if (valid) {
        float4 bb = *reinterpret_cast<const float4*>(b2 + l16 * 4);
        v[0] = acc[0] + s0.x * sl + bb.x;
        v[1] = acc[1] + s0.y * sl + bb.y;
        v[2] = acc[2] + s1.x * sl + bb.z;
        v[3] = acc[3] + s1.y * sl + bb.w;
    } else {
        v[0] = v[1] = v[2] = v[3] = -INFINITY;
    }
    float m = fmaxf(fmaxf(v[0], v[1]), fmaxf(v[2], v[3]));
    #pragma unroll
    for (int off = 8; off; off >>= 1) m = fmaxf(m, __shfl_xor(m, off, 64));
    float ex = expf(v[0] - m) + expf(v[1] - m) + expf(v[2] - m) + expf(v[3] - m);
    #pragma unroll
    for (int off = 8; off; off >>= 1) ex += __shfl_xor(ex, off, 64);
    float ls = logf(ex);
    if (lane < 16 && valid) {
        float4 o;
        o.x = v[0] - m - ls; o.y = v[1] - m - ls;
        o.z = v[2] - m - ls; o.w = v[3] - m - ls;
        *reinterpret_cast<float4*>(out + (size_t)node * NC + l16 * 4) = o;
    }
}

extern "C" void kernel_launch(void* const* d_in, const int* in_sizes, int n_in,
                              void* d_out, int out_size, void* d_ws, size_t ws_size,
                              hipStream_t stream) {
    const float* x  = (const float*)d_in[0];
    const int*   ei = (const int*)d_in[1];
    const float* W1 = (const float*)d_in[2];
    const float* b1 = (const float*)d_in[3];
    const float* W2 = (const float*)d_in[4];
    const float* b2 = (const float*)d_in[5];
    float* out = (float*)d_out;

    int*   counts  = (int*)d_ws;
    int*   offsets = counts + OFF_OFFSETS;
    int*   cursor  = counts + OFF_CURSOR;
    float* dinv    = (float*)(counts + OFF_DINV);
    int2*  erec    = (int2*)(counts + OFF_EREC);
    __hip_bfloat16* H    = (__hip_bfloat16*)(counts + OFF_H);
    __hip_bfloat16* W1t  = (__hip_bfloat16*)(counts + OFF_W1T);
    float*          Hagg = (float*)(counts + OFF_HAGG);
    __hip_bfloat16* H2p  = H;                  // padded [NN][64] bf16, reuses H after agg1

    int* blocksums = counts + OFF_H;           // scan scratch (before gemm1 writes H)
    int* blockpref = counts + OFF_H + 128;

    // 1. CSR build (count fused with W1 prep; dinv fused into scan phase 3)
    (void)hipMemsetAsync(counts, 0, NN * sizeof(int), stream);
    count_prep<<<BUCKET_NB, 256, 0, stream>>>(ei + NE, counts, W1, W1t);
    scan_phase1<<<SCAN_NB, SCAN_TILE, 0, stream>>>(counts, blocksums);
    scan_phase2<<<1, 128, 0, stream>>>(blocksums, blockpref);
    scan_phase3<<<SCAN_NB, SCAN_TILE, 0, stream>>>(counts, blockpref, offsets, cursor, dinv);

    // 2. FUSED: bucket scatter + H = bf16(x @ W1) via MFMA (independent, overlap in one kernel)
    bucket_gemm1<<<GEMM1_NB + BUCKET_NB, 256, 0, stream>>>(ei, dinv, cursor, erec, x, W1t, H);

    // 3. layer-1 gather (fused self-loop + bias + relu) -> Hagg (fp32)
    {
        long long threads = (long long)NN * 64;
        agg1_gather<<<(unsigned)((threads + 255) / 256), 256, 0, stream>>>(
            offsets, erec, dinv, H, b1, Hagg);
    }

    // 4. H2p = bf16(Hagg @ W2) padded to 64 cols (pad = 0)
    gemm2_pad<<<(NN + 63) / 64, 256, 0, stream>>>(Hagg, W2, H2p, NN);

    // 5. layer-2 gather + self + bias + log_softmax -> out
    {
        long long threads = (long long)NN * 64;
        agg2_lsm<<<(unsigned)((threads + 255) / 256), 256, 0, stream>>>(
            offsets, erec, dinv, H2p, b2, out);
    }
}

// Round 9
// 480.009 us; speedup vs baseline: 1.6885x; 1.0075x over previous
//
#include <hip/hip_runtime.h>
#include <hip/hip_bf16.h>
#include <math.h>

#define NN 100000      // nodes
#define NE 1600000     // edges
#define NF 256         // input features
#define NH 128         // hidden
#define NC 40          // classes
#define NCP 64         // padded classes (128-B rows)

// Workspace layout (4-byte units):
//   counts     [0,       100032)
//   offsets    [100032,  200128)   (NN+1 used)
//   bin_cursor [200128,  300160)   (NBINS used)
//   dinv       [300160,  400192)
//   erec       [400192,  3600192)  (NE int2)
//   H          [3600192, 10000192) (bf16 NN*NH; scan scratch early; padded H2 after agg1)
//   w1t        [10000192,10016576)
//   Hagg       [16400192,29200192) (NN*NH floats; ebin [NE ints] lives here before agg1)
#define OFF_OFFSETS 100032
#define OFF_CURSOR  200128
#define OFF_DINV    300160
#define OFF_EREC    400192
#define OFF_H       3600192
#define OFF_W1T     10000192
#define OFF_HAGG    16400192

#define SCAN_TILE 1024
#define SCAN_NB   ((NN + SCAN_TILE - 1) / SCAN_TILE)   // 98

#define GEMM1_NB  ((NN + 127) / 128)    // 782
#define NBINS     ((NN + 255) / 256)    // 391
#define CHUNK_A   16384
#define NB_A      ((NE + CHUNK_A - 1) / CHUNK_A)       // 98

using f32x4  = __attribute__((ext_vector_type(4))) float;
using bf16x8 = __attribute__((ext_vector_type(8))) short;

// decode packed pair of bf16 (lo, hi) to fp32x2 — exact, pure bit ops
__device__ inline float2 cvt2(unsigned u) {
    float2 f;
    f.x = __uint_as_float(u << 16);
    f.y = __uint_as_float(u & 0xffff0000u);
    return f;
}

__device__ inline short bfbits(float f) {
    __hip_bfloat16 h = __float2bfloat16(f);
    return *reinterpret_cast<short*>(&h);
}

// ---------------- count + W1 transpose/convert (fused, independent work) ----------------
__global__ void count_prep(const int* __restrict__ dst, int* __restrict__ count,
                           const float* __restrict__ W1, __hip_bfloat16* __restrict__ W1t) {
    int t = blockIdx.x * blockDim.x + threadIdx.x;
    if (t < NE) atomicAdd(&count[dst[t]], 1);
    if (t < NH * NF) {
        int n = t >> 8;
        int k = t & (NF - 1);
        W1t[t] = __float2bfloat16(W1[(size_t)k * NH + n]);
    }
}

// ---- hierarchical scan ----
__global__ void scan_phase1(const int* __restrict__ count, int* __restrict__ blocksums) {
    int b = blockIdx.x, t = threadIdx.x;
    int i = b * SCAN_TILE + t;
    int v = (i < NN) ? count[i] : 0;
    #pragma unroll
    for (int off = 32; off; off >>= 1) v += __shfl_xor(v, off, 64);
    __shared__ int ws[16];
    int lane = t & 63, wave = t >> 6;
    if (lane == 0) ws[wave] = v;
    __syncthreads();
    if (t == 0) {
        int s = 0;
        #pragma unroll
        for (int w = 0; w < SCAN_TILE / 64; ++w) s += ws[w];
        blocksums[b] = s;
    }
}

__global__ void scan_phase2(const int* __restrict__ blocksums, int* __restrict__ blockpref) {
    __shared__ int s[128];
    int t = threadIdx.x;
    int v = (t < SCAN_NB) ? blocksums[t] : 0;
    s[t] = v;
    __syncthreads();
    for (int off = 1; off < 128; off <<= 1) {
        int u = (t >= off) ? s[t - off] : 0;
        __syncthreads();
        s[t] += u;
        __syncthreads();
    }
    if (t < SCAN_NB) blockpref[t] = s[t] - v;
}

// phase 3: offsets + dinv + per-bin cursor bases (offsets at bin boundaries)
__global__ void scan_phase3(const int* __restrict__ count, const int* __restrict__ blockpref,
                            int* __restrict__ offsets, int* __restrict__ bin_cursor,
                            float* __restrict__ dinv) {
    int b = blockIdx.x, t = threadIdx.x;
    int i = b * SCAN_TILE + t;
    int v = (i < NN) ? count[i] : 0;
    int lane = t & 63, wave = t >> 6;
    int s = v;
    #pragma unroll
    for (int off = 1; off < 64; off <<= 1) {
        int u = __shfl_up(s, off, 64);
        if (lane >= off) s += u;
    }
    __shared__ int wsum[16];
    if (lane == 63) wsum[wave] = s;
    __syncthreads();
    if (t < 16) {
        int x = wsum[t];
        #pragma unroll
        for (int off = 1; off < 16; off <<= 1) {
            int u = __shfl_up(x, off, 64);
            if (t >= off) x += u;
        }
        wsum[t] = x;
    }
    __syncthreads();
    int excl = (s - v) + (wave ? wsum[wave - 1] : 0) + blockpref[b];
    if (i < NN) {
        offsets[i] = excl;
        dinv[i]    = rsqrtf((float)v + 1.0f);   // +1 self loop
        if ((i & 255) == 0) bin_cursor[i >> 8] = excl;
        if (i == NN - 1) offsets[NN] = excl + v;
    }
}

// ---------------- FUSED: layer-1 MFMA GEMM + pass A (coarse bin partition) ----------------
__global__ __launch_bounds__(256, 4) void gemm1_passA(
        const int* __restrict__ ei, int* __restrict__ bin_cursor,
        int* __restrict__ ebin,
        const float* __restrict__ X, const __hip_bfloat16* __restrict__ W1t,
        __hip_bfloat16* __restrict__ H) {
    __shared__ __align__(16) float As[128 * 32];
    __shared__ __align__(16) short Bs[128 * 32];
    __shared__ int hist[NBINS];
    __shared__ int rbase[NBINS];

    if (blockIdx.x >= GEMM1_NB) {
        // ---- pass A: partition edges into 256-node bins, run-coalesced writes ----
        int blk = blockIdx.x - GEMM1_NB;
        int e0 = blk * CHUNK_A;
        int e1 = e0 + CHUNK_A; if (e1 > NE) e1 = NE;
        for (int i = threadIdx.x; i < NBINS; i += 256) hist[i] = 0;
        __syncthreads();
        for (int p = e0 + threadIdx.x; p < e1; p += 256) {
            int d = ei[NE + p];
            atomicAdd(&hist[d >> 8], 1);
        }
        __syncthreads();
        for (int i = threadIdx.x; i < NBINS; i += 256) {
            int c = hist[i];
            rbase[i] = c ? atomicAdd(&bin_cursor[i], c) : 0;
        }
        __syncthreads();
        for (int p = e0 + threadIdx.x; p < e1; p += 256) {
            int s = ei[p];
            int d = ei[NE + p];
            int b = d >> 8;
            int pos = atomicAdd(&rbase[b], 1);
            ebin[pos] = s | ((d & 255) << 17);
        }
        return;
    }

    // ---- gemm1 path: H = bf16(x @ W1), 128x128 tile ----
    const int tid  = threadIdx.x;
    const int wave = tid >> 6;
    const int lane = tid & 63;
    const int quad = lane >> 4;
    const int l16  = lane & 15;
    const int wy = wave >> 1, wx = wave & 1;
    const int m0 = blockIdx.x * 128;

    f32x4 acc[4][4] = {};

    for (int k0 = 0; k0 < NF; k0 += 32) {
        #pragma unroll
        for (int i = 0; i < 4; ++i) {
            int c   = i * 256 + tid;
            int row = c >> 3, cc = c & 7;
            int gr  = m0 + row; if (gr > NN - 1) gr = NN - 1;
            const float* gp = X + (size_t)gr * NF + k0 + cc * 4;
            __builtin_amdgcn_global_load_lds(
                (const __attribute__((address_space(1))) void*)gp,
                (__attribute__((address_space(3))) void*)&As[(i * 256 + wave * 64) * 4],
                16, 0, 0);
        }
        #pragma unroll
        for (int i = 0; i < 2; ++i) {
            int c = i * 256 + tid;
            int n = c >> 2, cc = c & 3;
            const __hip_bfloat16* gp = W1t + (size_t)n * NF + k0 + cc * 8;
            __builtin_amdgcn_global_load_lds(
                (const __attribute__((address_space(1))) void*)gp,
                (__attribute__((address_space(3))) void*)&Bs[(i * 256 + wave * 64) * 8],
                16, 0, 0);
        }
        __syncthreads();

        bf16x8 a_frag[4], b_frag[4];
        #pragma unroll
        for (int mi = 0; mi < 4; ++mi) {
            const float* ap = &As[(wy * 64 + mi * 16 + l16) * 32 + quad * 8];
            f32x4 a0 = *(const f32x4*)ap;
            f32x4 a1 = *(const f32x4*)(ap + 4);
            bf16x8 af;
            af[0] = bfbits(a0.x); af[1] = bfbits(a0.y);
            af[2] = bfbits(a0.z); af[3] = bfbits(a0.w);
            af[4] = bfbits(a1.x); af[5] = bfbits(a1.y);
            af[6] = bfbits(a1.z); af[7] = bfbits(a1.w);
            a_frag[mi] = af;
        }
        #pragma unroll
        for (int ni = 0; ni < 4; ++ni) {
            const short* bp = &Bs[(wx * 64 + ni * 16 + l16) * 32 + quad * 8];
            b_frag[ni] = *(const bf16x8*)bp;
        }
        #pragma unroll
        for (int mi = 0; mi < 4; ++mi)
            #pragma unroll
            for (int ni = 0; ni < 4; ++ni)
                acc[mi][ni] = __builtin_amdgcn_mfma_f32_16x16x32_bf16(
                    a_frag[mi], b_frag[ni], acc[mi][ni], 0, 0, 0);
        __syncthreads();
    }

    #pragma unroll
    for (int mi = 0; mi < 4; ++mi)
        #pragma unroll
        for (int v = 0; v < 4; ++v) {
            int r = m0 + wy * 64 + mi * 16 + quad * 4 + v;
            if (r < NN) {
                #pragma unroll
                for (int ni = 0; ni < 4; ++ni) {
                    int c = wx * 64 + ni * 16 + l16;
                    H[(size_t)r * NH + c] = __float2bfloat16(acc[mi][ni][v]);
                }
            }
        }
}

// ---------------- pass B: within-bin counting sort -> erec (L2-local writes) ----------------
__global__ __launch_bounds__(256) void passB(const int* __restrict__ offsets,
                                             const int* __restrict__ ebin,
                                             const float* __restrict__ dinv,
                                             int2* __restrict__ erec) {
    int b = blockIdx.x;
    int n0 = b << 8;
    int nodes = NN - n0; if (nodes > 256) nodes = 256;
    __shared__ int cur[256];
    __shared__ float dls[256];
    if (threadIdx.x < nodes) {
        cur[threadIdx.x] = offsets[n0 + threadIdx.x];
        dls[threadIdx.x] = dinv[n0 + threadIdx.x];
    }
    __syncthreads();
    int binstart = offsets[n0];
    int binend   = offsets[n0 + nodes];
    for (int p = binstart + threadIdx.x; p < binend; p += 256) {
        int e  = ebin[p];
        int s  = e & 0x1FFFF;
        int dl = e >> 17;
        int pos = atomicAdd(&cur[dl], 1);
        float w = dinv[s] * dls[dl];
        erec[pos] = make_int2(s, __float_as_int(w));
    }
}

// ---------------- layer-2 GEMM (fp32 VALU), padded 64-wide bf16 output ----------------
__global__ void gemm2_pad(const float* __restrict__ A, const float* __restrict__ B,
                          __hip_bfloat16* __restrict__ C, int M) {
    constexpr int BM = 64, BN = 64, BK = 16, TM = 4, TN = 4;
    constexpr int THREADS = (BM / TM) * (BN / TN);
    __shared__ float sA[BK][BM + 1];
    __shared__ float sB[BK][BN];
    const int tid  = threadIdx.x;
    const int tcol = tid % (BN / TN);
    const int trow = tid / (BN / TN);
    const int row0 = blockIdx.x * BM;

    float acc[TM][TN];
    #pragma unroll
    for (int i = 0; i < TM; ++i)
        #pragma unroll
        for (int j = 0; j < TN; ++j) acc[i][j] = 0.f;

    for (int k0 = 0; k0 < NH; k0 += BK) {
        #pragma unroll
        for (int idx = tid; idx < BM * BK; idx += THREADS) {
            int m = idx / BK, kk = idx % BK;
            int r = row0 + m;
            sA[kk][m] = (r < M) ? A[(size_t)r * NH + k0 + kk] : 0.f;
        }
        #pragma unroll
        for (int idx = tid; idx < BK * BN; idx += THREADS) {
            int kk = idx / BN, c = idx % BN;
            sB[kk][c] = (c < NC) ? B[(size_t)(k0 + kk) * NC + c] : 0.f;
        }
        __syncthreads();
        #pragma unroll
        for (int kk = 0; kk < BK; ++kk) {
            float a[TM], b[TN];
            #pragma unroll
            for (int i = 0; i < TM; ++i) a[i] = sA[kk][trow * TM + i];
            #pragma unroll
            for (int j = 0; j < TN; ++j) b[j] = sB[kk][tcol * TN + j];
            #pragma unroll
            for (int i = 0; i < TM; ++i)
                #pragma unroll
                for (int j = 0; j < TN; ++j) acc[i][j] += a[i] * b[j];
        }
        __syncthreads();
    }

    #pragma unroll
    for (int i = 0; i < TM; ++i) {
        int r = row0 + trow * TM + i;
        if (r >= M) continue;
        #pragma unroll
        for (int j = 0; j < TN; ++j) {
            int c = tcol * TN + j;
            C[(size_t)r * NCP + c] = __float2bfloat16(acc[i][j]);
        }
    }
}

// ---------------- layer-1 gather: wave per node, 4 groups x 16 lanes, 2 edges in flight/group ----------------
__global__ void agg1_gather(const int* __restrict__ offsets, const int2* __restrict__ erec,
                            const float* __restrict__ dinv, const __hip_bfloat16* __restrict__ H,
                            const float* __restrict__ b1, float* __restrict__ Hagg) {
    int node = (blockIdx.x * blockDim.x + threadIdx.x) >> 6;
    if (node >= NN) return;
    int lane = threadIdx.x & 63;
    int grp = lane >> 4, l16 = lane & 15;
    int beg = offsets[node], end = offsets[node + 1];
    const uint4* Hv = reinterpret_cast<const uint4*>(H);   // 8 bf16 per uint4, 16 per row
    float acc[8] = {};
    int p = beg + grp;
    for (; p + 4 < end; p += 8) {
        int2 r1 = erec[p];
        int2 r2 = erec[p + 4];
        float w1 = __int_as_float(r1.y);
        float w2 = __int_as_float(r2.y);
        uint4 h1 = Hv[(size_t)r1.x * 16 + l16];
        uint4 h2 = Hv[(size_t)r2.x * 16 + l16];
        float2 a0 = cvt2(h1.x), a1 = cvt2(h1.y), a2 = cvt2(h1.z), a3 = cvt2(h1.w);
        acc[0] += a0.x * w1; acc[1] += a0.y * w1;
        acc[2] += a1.x * w1; acc[3] += a1.y * w1;
        acc[4] += a2.x * w1; acc[5] += a2.y * w1;
        acc[6] += a3.x * w1; acc[7] += a3.y * w1;
        float2 c0 = cvt2(h2.x), c1 = cvt2(h2.y), c2 = cvt2(h2.z), c3 = cvt2(h2.w);
        acc[0] += c0.x * w2; acc[1] += c0.y * w2;
        acc[2] += c1.x * w2; acc[3] += c1.y * w2;
        acc[4] += c2.x * w2; acc[5] += c2.y * w2;
        acc[6] += c3.x * w2; acc[7] += c3.y * w2;
    }
    if (p < end) {
        int2 r = erec[p];
        float w = __int_as_float(r.y);
        uint4 hv = Hv[(size_t)r.x * 16 + l16];
        float2 f0 = cvt2(hv.x), f1 = cvt2(hv.y), f2 = cvt2(hv.z), f3 = cvt2(hv.w);
        acc[0] += f0.x * w; acc[1] += f0.y * w;
        acc[2] += f1.x * w; acc[3] += f1.y * w;
        acc[4] += f2.x * w; acc[5] += f2.y * w;
        acc[6] += f3.x * w; acc[7] += f3.y * w;
    }
    #pragma unroll
    for (int k = 0; k < 8; ++k) {
        acc[k] += __shfl_xor(acc[k], 16, 64);
        acc[k] += __shfl_xor(acc[k], 32, 64);
    }
    if (lane < 16) {
        float di = dinv[node];
        float sl = di * di;
        uint4 hs = Hv[(size_t)node * 16 + l16];
        float2 s0 = cvt2(hs.x), s1 = cvt2(hs.y), s2 = cvt2(hs.z), s3 = cvt2(hs.w);
        const float4* bb = reinterpret_cast<const float4*>(b1 + l16 * 8);
        float4 ba = bb[0], bc = bb[1];
        float4 o0, o1;
        o0.x = fmaxf(acc[0] + s0.x * sl + ba.x, 0.f);
        o0.y = fmaxf(acc[1] + s0.y * sl + ba.y, 0.f);
        o0.z = fmaxf(acc[2] + s1.x * sl + ba.z, 0.f);
        o0.w = fmaxf(acc[3] + s1.y * sl + ba.w, 0.f);
        o1.x = fmaxf(acc[4] + s2.x * sl + bc.x, 0.f);
        o1.y = fmaxf(acc[5] + s2.y * sl + bc.y, 0.f);
        o1.z = fmaxf(acc[6] + s3.x * sl + bc.z, 0.f);
        o1.w = fmaxf(acc[7] + s3.y * sl + bc.w, 0.f);
        float4* op = reinterpret_cast<float4*>(Hagg + (size_t)node * NH + l16 * 8);
        op[0] = o0;
        op[1] = o1;
    }
}

// ---------------- layer-2 gather + self + bias + log_softmax (padded H2) ----------------
__global__ void agg2_lsm(const int* __restrict__ offsets, const int2* __restrict__ erec,
                         const float* __restrict__ dinv, const __hip_bfloat16* __restrict__ H2p,
                         const float* __restrict__ b2, float* __restrict__ out) {
    int node = (blockIdx.x * blockDim.x + threadIdx.x) >> 6;
    if (node >= NN) return;
    int lane = threadIdx.x & 63;
    int grp = lane >> 4, l16 = lane & 15;
    int beg = offsets[node], end = offsets[node + 1];
    const uint2* Hv = reinterpret_cast<const uint2*>(H2p);  // 4 bf16 per uint2, 16 per row
    float acc[4] = {};
    int p = beg + grp;
    for (; p + 4 < end; p += 8) {
        int2 r1 = erec[p];
        int2 r2 = erec[p + 4];
        float w1 = __int_as_float(r1.y);
        float w2 = __int_as_float(r2.y);
        uint2 h1 = Hv[(size_t)r1.x * 16 + l16];
        uint2 h2 = Hv[(size_t)r2.x * 16 + l16];
        float2 a0 = cvt2(h1.x), a1 = cvt2(h1.y);
        acc[0] += a0.x * w1; acc[1] += a0.y * w1;
        acc[2] += a1.x * w1; acc[3] += a1.y * w1;
        float2 c0 = cvt2(h2.x), c1 = cvt2(h2.y);
        acc[0] += c0.x * w2; acc[1] += c0.y * w2;
        acc[2] += c1.x * w2; acc[3] += c1.y * w2;
    }
    if (p < end) {
        int2 r = erec[p];
        float w = __int_as_float(r.y);
        uint2 hv = Hv[(size_t)r.x * 16 + l16];
        float2 f0 = cvt2(hv.x), f1 = cvt2(hv.y);
        acc[0] += f0.x * w; acc[1] += f0.y * w;
        acc[2] += f1.x * w; acc[3] += f1.y * w;
    }
    #pragma unroll
    for (int k = 0; k < 4; ++k) {
        acc[k] += __shfl_xor(acc[k], 16, 64);
        acc[k] += __shfl_xor(acc[k], 32, 64);
    }
    float di = dinv[node];
    float sl = di * di;
    uint2 hs = Hv[(size_t)node * 16 + l16];
    float2 s0 = cvt2(hs.x), s1 = cvt2(hs.y);
    float v[4];
    bool valid = (l16 < 10);   // classes l16*4..l16*4+3 < 40
    if (valid) {
        float4 bb = *reinterpret_cast<const float4*>(b2 + l16 * 4);
        v[0] = acc[0] + s0.x * sl + bb.x;
        v[1] = acc[1] + s0.y * sl + bb.y;
        v[2] = acc[2] + s1.x * sl + bb.z;
        v[3] = acc[3] + s1.y * sl + bb.w;
    } else {
        v[0] = v[1] = v[2] = v[3] = -INFINITY;
    }
    float m = fmaxf(fmaxf(v[0], v[1]), fmaxf(v[2], v[3]));
    #pragma unroll
    for (int off = 8; off; off >>= 1) m = fmaxf(m, __shfl_xor(m, off, 64));
    float ex = expf(v[0] - m) + expf(v[1] - m) + expf(v[2] - m) + expf(v[3] - m);
    #pragma unroll
    for (int off = 8; off; off >>= 1) ex += __shfl_xor(ex, off, 64);
    float ls = logf(ex);
    if (lane < 16 && valid) {
        float4 o;
        o.x = v[0] - m - ls; o.y = v[1] - m - ls;
        o.z = v[2] - m - ls; o.w = v[3] - m - ls;
        *reinterpret_cast<float4*>(out + (size_t)node * NC + l16 * 4) = o;
    }
}

extern "C" void kernel_launch(void* const* d_in, const int* in_sizes, int n_in,
                              void* d_out, int out_size, void* d_ws, size_t ws_size,
                              hipStream_t stream) {
    const float* x  = (const float*)d_in[0];
    const int*   ei = (const int*)d_in[1];
    const float* W1 = (const float*)d_in[2];
    const float* b1 = (const float*)d_in[3];
    const float* W2 = (const float*)d_in[4];
    const float* b2 = (const float*)d_in[5];
    float* out = (float*)d_out;

    int*   counts     = (int*)d_ws;
    int*   offsets    = counts + OFF_OFFSETS;
    int*   bin_cursor = counts + OFF_CURSOR;
    float* dinv       = (float*)(counts + OFF_DINV);
    int2*  erec       = (int2*)(counts + OFF_EREC);
    __hip_bfloat16* H    = (__hip_bfloat16*)(counts + OFF_H);
    __hip_bfloat16* W1t  = (__hip_bfloat16*)(counts + OFF_W1T);
    float*          Hagg = (float*)(counts + OFF_HAGG);
    int*            ebin = counts + OFF_HAGG;   // dead before agg1 writes Hagg
    __hip_bfloat16* H2p  = H;                   // padded [NN][64] bf16, reuses H after agg1

    int* blocksums = counts + OFF_H;            // scan scratch (before gemm1 writes H)
    int* blockpref = counts + OFF_H + 128;

    // 1. CSR build: count+W1t prep, then scan (offsets, dinv, bin cursor bases)
    (void)hipMemsetAsync(counts, 0, NN * sizeof(int), stream);
    count_prep<<<(NE + 255) / 256, 256, 0, stream>>>(ei + NE, counts, W1, W1t);
    scan_phase1<<<SCAN_NB, SCAN_TILE, 0, stream>>>(counts, blocksums);
    scan_phase2<<<1, 128, 0, stream>>>(blocksums, blockpref);
    scan_phase3<<<SCAN_NB, SCAN_TILE, 0, stream>>>(counts, blockpref, offsets, bin_cursor, dinv);

    // 2. FUSED: gemm1 (MFMA) + pass A coarse binning (independent work, one kernel)
    gemm1_passA<<<GEMM1_NB + NB_A, 256, 0, stream>>>(ei, bin_cursor, ebin, x, W1t, H);

    // 2b. pass B: within-bin sort -> erec (one block per bin, L2-local writes)
    passB<<<NBINS, 256, 0, stream>>>(offsets, ebin, dinv, erec);

    // 3. layer-1 gather (fused self-loop + bias + relu) -> Hagg (fp32)
    {
        long long threads = (long long)NN * 64;
        agg1_gather<<<(unsigned)((threads + 255) / 256), 256, 0, stream>>>(
            offsets, erec, dinv, H, b1, Hagg);
    }

    // 4. H2p = bf16(Hagg @ W2) padded to 64 cols (pad = 0)
    gemm2_pad<<<(NN + 63) / 64, 256, 0, stream>>>(Hagg, W2, H2p, NN);

    // 5. layer-2 gather + self + bias + log_softmax -> out
    {
        long long threads = (long long)NN * 64;
        agg2_lsm<<<(unsigned)((threads + 255) / 256), 256, 0, stream>>>(
            offsets, erec, dinv, H2p, b2, out);
    }
}

// Round 10
// 419.773 us; speedup vs baseline: 1.9308x; 1.1435x over previous
//
#include <hip/hip_runtime.h>
#include <hip/hip_bf16.h>
#include <math.h>

#define NN 100000      // nodes
#define NE 1600000     // edges
#define NF 256         // input features
#define NH 128         // hidden
#define NC 40          // classes
#define NCP 64         // padded classes (128-B rows)

// Workspace layout (4-byte units):
//   counts     [0,       100032)
//   offsets    [100032,  200128)   (NN+1 used)
//   bin_cursor [200128,  300160)   (NBINS used)
//   dinv       [300160,  400192)
//   erec       [400192,  3600192)  (NE int2)
//   H          [3600192, 10000192) (bf16 NN*NH; scan scratch early; padded H2 after agg1)
//   w1t        [10000192,10016576) (bf16 [128][256])
//   w2t        [10016576,10020672) (bf16 [64][128], rows >=40 zero)
//   Hagg       [16400192,29200192) (bf16 NN*NH after agg1; ebin [NE ints] lives here first)
#define OFF_OFFSETS 100032
#define OFF_CURSOR  200128
#define OFF_DINV    300160
#define OFF_EREC    400192
#define OFF_H       3600192
#define OFF_W1T     10000192
#define OFF_W2T     10016576
#define OFF_HAGG    16400192

#define SCAN_TILE 1024
#define SCAN_NB   ((NN + SCAN_TILE - 1) / SCAN_TILE)   // 98

#define GEMM1_NB  ((NN + 127) / 128)    // 782
#define NBINS     ((NN + 255) / 256)    // 391
#define CHUNK_A   4096
#define NB_A      ((NE + CHUNK_A - 1) / CHUNK_A)       // 391 (= GEMM1_NB/2)

using f32x4  = __attribute__((ext_vector_type(4))) float;
using bf16x8 = __attribute__((ext_vector_type(8))) short;

// decode packed pair of bf16 (lo, hi) to fp32x2 — exact, pure bit ops
__device__ inline float2 cvt2(unsigned u) {
    float2 f;
    f.x = __uint_as_float(u << 16);
    f.y = __uint_as_float(u & 0xffff0000u);
    return f;
}

__device__ inline short bfbits(float f) {
    __hip_bfloat16 h = __float2bfloat16(f);
    return *reinterpret_cast<short*>(&h);
}

__device__ inline unsigned pk2(float lo, float hi) {
    return (unsigned)(unsigned short)bfbits(lo) | ((unsigned)(unsigned short)bfbits(hi) << 16);
}

// ---------------- count + W1t/W2t prep (fused, independent work) ----------------
__global__ void count_prep(const int* __restrict__ dst, int* __restrict__ count,
                           const float* __restrict__ W1, __hip_bfloat16* __restrict__ W1t,
                           const float* __restrict__ W2, __hip_bfloat16* __restrict__ W2t) {
    int t = blockIdx.x * blockDim.x + threadIdx.x;
    if (t < NE) atomicAdd(&count[dst[t]], 1);
    if (t < NH * NF) {
        int n = t >> 8;
        int k = t & (NF - 1);
        W1t[t] = __float2bfloat16(W1[(size_t)k * NH + n]);
    }
    if (t < NCP * NH) {
        int n = t >> 7;
        int k = t & (NH - 1);
        W2t[t] = __float2bfloat16((n < NC) ? W2[(size_t)k * NC + n] : 0.f);
    }
}

// ---- hierarchical scan ----
__global__ void scan_phase1(const int* __restrict__ count, int* __restrict__ blocksums) {
    int b = blockIdx.x, t = threadIdx.x;
    int i = b * SCAN_TILE + t;
    int v = (i < NN) ? count[i] : 0;
    #pragma unroll
    for (int off = 32; off; off >>= 1) v += __shfl_xor(v, off, 64);
    __shared__ int ws[16];
    int lane = t & 63, wave = t >> 6;
    if (lane == 0) ws[wave] = v;
    __syncthreads();
    if (t == 0) {
        int s = 0;
        #pragma unroll
        for (int w = 0; w < SCAN_TILE / 64; ++w) s += ws[w];
        blocksums[b] = s;
    }
}

__global__ void scan_phase2(const int* __restrict__ blocksums, int* __restrict__ blockpref) {
    __shared__ int s[128];
    int t = threadIdx.x;
    int v = (t < SCAN_NB) ? blocksums[t] : 0;
    s[t] = v;
    __syncthreads();
    for (int off = 1; off < 128; off <<= 1) {
        int u = (t >= off) ? s[t - off] : 0;
        __syncthreads();
        s[t] += u;
        __syncthreads();
    }
    if (t < SCAN_NB) blockpref[t] = s[t] - v;
}

// phase 3: offsets + dinv + per-bin cursor bases
__global__ void scan_phase3(const int* __restrict__ count, const int* __restrict__ blockpref,
                            int* __restrict__ offsets, int* __restrict__ bin_cursor,
                            float* __restrict__ dinv) {
    int b = blockIdx.x, t = threadIdx.x;
    int i = b * SCAN_TILE + t;
    int v = (i < NN) ? count[i] : 0;
    int lane = t & 63, wave = t >> 6;
    int s = v;
    #pragma unroll
    for (int off = 1; off < 64; off <<= 1) {
        int u = __shfl_up(s, off, 64);
        if (lane >= off) s += u;
    }
    __shared__ int wsum[16];
    if (lane == 63) wsum[wave] = s;
    __syncthreads();
    if (t < 16) {
        int x = wsum[t];
        #pragma unroll
        for (int off = 1; off < 16; off <<= 1) {
            int u = __shfl_up(x, off, 64);
            if (t >= off) x += u;
        }
        wsum[t] = x;
    }
    __syncthreads();
    int excl = (s - v) + (wave ? wsum[wave - 1] : 0) + blockpref[b];
    if (i < NN) {
        offsets[i] = excl;
        dinv[i]    = rsqrtf((float)v + 1.0f);   // +1 self loop
        if ((i & 255) == 0) bin_cursor[i >> 8] = excl;
        if (i == NN - 1) offsets[NN] = excl + v;
    }
}

// ---------------- FUSED + INTERLEAVED: layer-1 MFMA GEMM + pass A coarse binning ----------------
// Block pattern (3k blocks): b%3==1 -> passA chunk b/3; else gemm tile 2*(b/3)+(b%3==2)
__global__ __launch_bounds__(256, 4) void gemm1_passA(
        const int* __restrict__ ei, int* __restrict__ bin_cursor,
        int* __restrict__ ebin,
        const float* __restrict__ X, const __hip_bfloat16* __restrict__ W1t,
        __hip_bfloat16* __restrict__ H) {
    __shared__ __align__(16) int smem[6144];   // 24 KB: gemm As(16K)+Bs(8K) OR passA hist/rbase

    const int bi = blockIdx.x / 3;
    const int br = blockIdx.x % 3;

    if (br == 1) {
        // ---- pass A: partition 4096 edges into 256-node bins, run-coalesced writes ----
        int* hist  = smem;
        int* rbase = smem + NBINS;
        int e0 = bi * CHUNK_A;
        int e1 = e0 + CHUNK_A; if (e1 > NE) e1 = NE;
        for (int j = threadIdx.x; j < NBINS; j += 256) hist[j] = 0;
        __syncthreads();
        for (int p = e0 + threadIdx.x; p < e1; p += 256)
            atomicAdd(&hist[ei[NE + p] >> 8], 1);
        __syncthreads();
        for (int j = threadIdx.x; j < NBINS; j += 256) {
            int c = hist[j];
            rbase[j] = c ? atomicAdd(&bin_cursor[j], c) : 0;
        }
        __syncthreads();
        for (int p = e0 + threadIdx.x; p < e1; p += 256) {
            int s = ei[p];
            int d = ei[NE + p];
            int bb = d >> 8;
            int pos = atomicAdd(&rbase[bb], 1);
            ebin[pos] = s | ((d & 255) << 17);
        }
        return;
    }

    // ---- gemm1 path: H = bf16(x @ W1), 128x128 tile ----
    float* As = (float*)smem;          // [128][32] fp32
    short* Bs = (short*)(smem + 4096); // [128][32] bf16

    const int tid  = threadIdx.x;
    const int wave = tid >> 6;
    const int lane = tid & 63;
    const int quad = lane >> 4;
    const int l16  = lane & 15;
    const int wy = wave >> 1, wx = wave & 1;
    const int m0 = (bi * 2 + (br == 2 ? 1 : 0)) * 128;

    f32x4 acc[4][4] = {};

    for (int k0 = 0; k0 < NF; k0 += 32) {
        #pragma unroll
        for (int i = 0; i < 4; ++i) {
            int c   = i * 256 + tid;
            int row = c >> 3, cc = c & 7;
            int gr  = m0 + row; if (gr > NN - 1) gr = NN - 1;
            const float* gp = X + (size_t)gr * NF + k0 + cc * 4;
            __builtin_amdgcn_global_load_lds(
                (const __attribute__((address_space(1))) void*)gp,
                (__attribute__((address_space(3))) void*)&As[(i * 256 + wave * 64) * 4],
                16, 0, 0);
        }
        #pragma unroll
        for (int i = 0; i < 2; ++i) {
            int c = i * 256 + tid;
            int n = c >> 2, cc = c & 3;
            const __hip_bfloat16* gp = W1t + (size_t)n * NF + k0 + cc * 8;
            __builtin_amdgcn_global_load_lds(
                (const __attribute__((address_space(1))) void*)gp,
                (__attribute__((address_space(3))) void*)&Bs[(i * 256 + wave * 64) * 8],
                16, 0, 0);
        }
        __syncthreads();

        bf16x8 a_frag[4], b_frag[4];
        #pragma unroll
        for (int mi = 0; mi < 4; ++mi) {
            const float* ap = &As[(wy * 64 + mi * 16 + l16) * 32 + quad * 8];
            f32x4 a0 = *(const f32x4*)ap;
            f32x4 a1 = *(const f32x4*)(ap + 4);
            bf16x8 af;
            af[0] = bfbits(a0.x); af[1] = bfbits(a0.y);
            af[2] = bfbits(a0.z); af[3] = bfbits(a0.w);
            af[4] = bfbits(a1.x); af[5] = bfbits(a1.y);
            af[6] = bfbits(a1.z); af[7] = bfbits(a1.w);
            a_frag[mi] = af;
        }
        #pragma unroll
        for (int ni = 0; ni < 4; ++ni) {
            const short* bp = &Bs[(wx * 64 + ni * 16 + l16) * 32 + quad * 8];
            b_frag[ni] = *(const bf16x8*)bp;
        }
        #pragma unroll
        for (int mi = 0; mi < 4; ++mi)
            #pragma unroll
            for (int ni = 0; ni < 4; ++ni)
                acc[mi][ni] = __builtin_amdgcn_mfma_f32_16x16x32_bf16(
                    a_frag[mi], b_frag[ni], acc[mi][ni], 0, 0, 0);
        __syncthreads();
    }

    #pragma unroll
    for (int mi = 0; mi < 4; ++mi)
        #pragma unroll
        for (int v = 0; v < 4; ++v) {
            int r = m0 + wy * 64 + mi * 16 + quad * 4 + v;
            if (r < NN) {
                #pragma unroll
                for (int ni = 0; ni < 4; ++ni) {
                    int c = wx * 64 + ni * 16 + l16;
                    H[(size_t)r * NH + c] = __float2bfloat16(acc[mi][ni][v]);
                }
            }
        }
}

// ---------------- pass B: within-bin counting sort -> erec (L2-local writes) ----------------
__global__ __launch_bounds__(256) void passB(const int* __restrict__ offsets,
                                             const int* __restrict__ ebin,
                                             const float* __restrict__ dinv,
                                             int2* __restrict__ erec) {
    int b = blockIdx.x;
    int n0 = b << 8;
    int nodes = NN - n0; if (nodes > 256) nodes = 256;
    __shared__ int cur[256];
    __shared__ float dls[256];
    if (threadIdx.x < nodes) {
        cur[threadIdx.x] = offsets[n0 + threadIdx.x];
        dls[threadIdx.x] = dinv[n0 + threadIdx.x];
    }
    __syncthreads();
    int binstart = offsets[n0];
    int binend   = offsets[n0 + nodes];
    for (int p = binstart + threadIdx.x; p < binend; p += 256) {
        int e  = ebin[p];
        int s  = e & 0x1FFFF;
        int dl = e >> 17;
        int pos = atomicAdd(&cur[dl], 1);
        float w = dinv[s] * dls[dl];
        erec[pos] = make_int2(s, __float_as_int(w));
    }
}

// ---------------- layer-2 GEMM via MFMA: H2p = bf16(Haggb @ W2pad), 128x64 tile ----------------
__global__ __launch_bounds__(256) void gemm2_mfma(const __hip_bfloat16* __restrict__ Haggb,
                                                  const __hip_bfloat16* __restrict__ W2t,
                                                  __hip_bfloat16* __restrict__ H2p) {
    __shared__ __align__(16) short As2[128 * 32];  // 8 KB
    __shared__ __align__(16) short Bs2[64 * 32];   // 4 KB
    const int tid  = threadIdx.x;
    const int wave = tid >> 6;
    const int lane = tid & 63;
    const int quad = lane >> 4;
    const int l16  = lane & 15;
    const int m0 = blockIdx.x * 128;

    f32x4 acc[2][4] = {};

    for (int k0 = 0; k0 < NH; k0 += 32) {
        // stage A: 128 rows x 32 bf16 = 512 x 16B chunks, 2 issues
        #pragma unroll
        for (int i = 0; i < 2; ++i) {
            int c = i * 256 + tid;
            int row = c >> 2, cc = c & 3;
            int gr = m0 + row; if (gr > NN - 1) gr = NN - 1;
            const __hip_bfloat16* gp = Haggb + (size_t)gr * NH + k0 + cc * 8;
            __builtin_amdgcn_global_load_lds(
                (const __attribute__((address_space(1))) void*)gp,
                (__attribute__((address_space(3))) void*)&As2[(i * 256 + wave * 64) * 8],
                16, 0, 0);
        }
        // stage B: 64 rows x 32 bf16 = 256 x 16B chunks, 1 issue
        {
            int c = tid;
            int row = c >> 2, cc = c & 3;
            const __hip_bfloat16* gp = W2t + (size_t)row * NH + k0 + cc * 8;
            __builtin_amdgcn_global_load_lds(
                (const __attribute__((address_space(1))) void*)gp,
                (__attribute__((address_space(3))) void*)&Bs2[(wave * 64) * 8],
                16, 0, 0);
        }
        __syncthreads();

        bf16x8 a_frag[2], b_frag[4];
        #pragma unroll
        for (int mi = 0; mi < 2; ++mi)
            a_frag[mi] = *(const bf16x8*)&As2[(wave * 32 + mi * 16 + l16) * 32 + quad * 8];
        #pragma unroll
        for (int ni = 0; ni < 4; ++ni)
            b_frag[ni] = *(const bf16x8*)&Bs2[(ni * 16 + l16) * 32 + quad * 8];
        #pragma unroll
        for (int mi = 0; mi < 2; ++mi)
            #pragma unroll
            for (int ni = 0; ni < 4; ++ni)
                acc[mi][ni] = __builtin_amdgcn_mfma_f32_16x16x32_bf16(
                    a_frag[mi], b_frag[ni], acc[mi][ni], 0, 0, 0);
        __syncthreads();
    }

    #pragma unroll
    for (int mi = 0; mi < 2; ++mi)
        #pragma unroll
        for (int v = 0; v < 4; ++v) {
            int r = m0 + wave * 32 + mi * 16 + quad * 4 + v;
            if (r < NN) {
                #pragma unroll
                for (int ni = 0; ni < 4; ++ni) {
                    int c = ni * 16 + l16;
                    H2p[(size_t)r * NCP + c] = __float2bfloat16(acc[mi][ni][v]);
                }
            }
        }
}

// ---------------- layer-1 gather: wave per node, 4 groups x 16 lanes, 2 edges in flight ----------------
__global__ void agg1_gather(const int* __restrict__ offsets, const int2* __restrict__ erec,
                            const float* __restrict__ dinv, const __hip_bfloat16* __restrict__ H,
                            const float* __restrict__ b1, __hip_bfloat16* __restrict__ Haggb) {
    int node = (blockIdx.x * blockDim.x + threadIdx.x) >> 6;
    if (node >= NN) return;
    int lane = threadIdx.x & 63;
    int grp = lane >> 4, l16 = lane & 15;
    int beg = offsets[node], end = offsets[node + 1];
    const uint4* Hv = reinterpret_cast<const uint4*>(H);   // 8 bf16 per uint4, 16 per row
    float acc[8] = {};
    int p = beg + grp;
    for (; p + 4 < end; p += 8) {
        int2 r1 = erec[p];
        int2 r2 = erec[p + 4];
        float w1 = __int_as_float(r1.y);
        float w2 = __int_as_float(r2.y);
        uint4 h1 = Hv[(size_t)r1.x * 16 + l16];
        uint4 h2 = Hv[(size_t)r2.x * 16 + l16];
        float2 a0 = cvt2(h1.x), a1 = cvt2(h1.y), a2 = cvt2(h1.z), a3 = cvt2(h1.w);
        acc[0] += a0.x * w1; acc[1] += a0.y * w1;
        acc[2] += a1.x * w1; acc[3] += a1.y * w1;
        acc[4] += a2.x * w1; acc[5] += a2.y * w1;
        acc[6] += a3.x * w1; acc[7] += a3.y * w1;
        float2 c0 = cvt2(h2.x), c1 = cvt2(h2.y), c2 = cvt2(h2.z), c3 = cvt2(h2.w);
        acc[0] += c0.x * w2; acc[1] += c0.y * w2;
        acc[2] += c1.x * w2; acc[3] += c1.y * w2;
        acc[4] += c2.x * w2; acc[5] += c2.y * w2;
        acc[6] += c3.x * w2; acc[7] += c3.y * w2;
    }
    if (p < end) {
        int2 r = erec[p];
        float w = __int_as_float(r.y);
        uint4 hv = Hv[(size_t)r.x * 16 + l16];
        float2 f0 = cvt2(hv.x), f1 = cvt2(hv.y), f2 = cvt2(hv.z), f3 = cvt2(hv.w);
        acc[0] += f0.x * w; acc[1] += f0.y * w;
        acc[2] += f1.x * w; acc[3] += f1.y * w;
        acc[4] += f2.x * w; acc[5] += f2.y * w;
        acc[6] += f3.x * w; acc[7] += f3.y * w;
    }
    #pragma unroll
    for (int k = 0; k < 8; ++k) {
        acc[k] += __shfl_xor(acc[k], 16, 64);
        acc[k] += __shfl_xor(acc[k], 32, 64);
    }
    if (lane < 16) {
        float di = dinv[node];
        float sl = di * di;
        uint4 hs = Hv[(size_t)node * 16 + l16];
        float2 s0 = cvt2(hs.x), s1 = cvt2(hs.y), s2 = cvt2(hs.z), s3 = cvt2(hs.w);
        const float4* bb = reinterpret_cast<const float4*>(b1 + l16 * 8);
        float4 ba = bb[0], bc = bb[1];
        float o0 = fmaxf(acc[0] + s0.x * sl + ba.x, 0.f);
        float o1 = fmaxf(acc[1] + s0.y * sl + ba.y, 0.f);
        float o2 = fmaxf(acc[2] + s1.x * sl + ba.z, 0.f);
        float o3 = fmaxf(acc[3] + s1.y * sl + ba.w, 0.f);
        float o4 = fmaxf(acc[4] + s2.x * sl + bc.x, 0.f);
        float o5 = fmaxf(acc[5] + s2.y * sl + bc.y, 0.f);
        float o6 = fmaxf(acc[6] + s3.x * sl + bc.z, 0.f);
        float o7 = fmaxf(acc[7] + s3.y * sl + bc.w, 0.f);
        uint4 ov;
        ov.x = pk2(o0, o1);
        ov.y = pk2(o2, o3);
        ov.z = pk2(o4, o5);
        ov.w = pk2(o6, o7);
        *reinterpret_cast<uint4*>(Haggb + (size_t)node * NH + l16 * 8) = ov;
    }
}

// ---------------- layer-2 gather + self + bias + log_softmax (padded H2) ----------------
__global__ void agg2_lsm(const int* __restrict__ offsets, const int2* __restrict__ erec,
                         const float* __restrict__ dinv, const __hip_bfloat16* __restrict__ H2p,
                         const float* __restrict__ b2, float* __restrict__ out) {
    int node = (blockIdx.x * blockDim.x + threadIdx.x) >> 6;
    if (node >= NN) return;
    int lane = threadIdx.x & 63;
    int grp = lane >> 4, l16 = lane & 15;
    int beg = offsets[node], end = offsets[node + 1];
    const uint2* Hv = reinterpret_cast<const uint2*>(H2p);  // 4 bf16 per uint2, 16 per row
    float acc[4] = {};
    int p = beg + grp;
    for (; p + 4 < end; p += 8) {
        int2 r1 = erec[p];
        int2 r2 = erec[p + 4];
        float w1 = __int_as_float(r1.y);
        float w2 = __int_as_float(r2.y);
        uint2 h1 = Hv[(size_t)r1.x * 16 + l16];
        uint2 h2 = Hv[(size_t)r2.x * 16 + l16];
        float2 a0 = cvt2(h1.x), a1 = cvt2(h1.y);
        acc[0] += a0.x * w1; acc[1] += a0.y * w1;
        acc[2] += a1.x * w1; acc[3] += a1.y * w1;
        float2 c0 = cvt2(h2.x), c1 = cvt2(h2.y);
        acc[0] += c0.x * w2; acc[1] += c0.y * w2;
        acc[2] += c1.x * w2; acc[3] += c1.y * w2;
    }
    if (p < end) {
        int2 r = erec[p];
        float w = __int_as_float(r.y);
        uint2 hv = Hv[(size_t)r.x * 16 + l16];
        float2 f0 = cvt2(hv.x), f1 = cvt2(hv.y);
        acc[0] += f0.x * w; acc[1] += f0.y * w;
        acc[2] += f1.x * w; acc[3] += f1.y * w;
    }
    #pragma unroll
    for (int k = 0; k < 4; ++k) {
        acc[k] += __shfl_xor(acc[k], 16, 64);
        acc[k] += __shfl_xor(acc[k], 32, 64);
    }
    float di = dinv[node];
    float sl = di * di;
    uint2 hs = Hv[(size_t)node * 16 + l16];
    float2 s0 = cvt2(hs.x), s1 = cvt2(hs.y);
    float v[4];
    bool valid = (l16 < 10);   // classes l16*4..l16*4+3 < 40
    if (valid) {
        float4 bb = *reinterpret_cast<const float4*>(b2 + l16 * 4);
        v[0] = acc[0] + s0.x * sl + bb.x;
        v[1] = acc[1] + s0.y * sl + bb.y;
        v[2] = acc[2] + s1.x * sl + bb.z;
        v[3] = acc[3] + s1.y * sl + bb.w;
    } else {
        v[0] = v[1] = v[2] = v[3] = -INFINITY;
    }
    float m = fmaxf(fmaxf(v[0], v[1]), fmaxf(v[2], v[3]));
    #pragma unroll
    for (int off = 8; off; off >>= 1) m = fmaxf(m, __shfl_xor(m, off, 64));
    float ex = expf(v[0] - m) + expf(v[1] - m) + expf(v[2] - m) + expf(v[3] - m);
    #pragma unroll
    for (int off = 8; off; off >>= 1) ex += __shfl_xor(ex, off, 64);
    float ls = logf(ex);
    if (lane < 16 && valid) {
        float4 o;
        o.x = v[0] - m - ls; o.y = v[1] - m - ls;
        o.z = v[2] - m - ls; o.w = v[3] - m - ls;
        *reinterpret_cast<float4*>(out + (size_t)node * NC + l16 * 4) = o;
    }
}

extern "C" void kernel_launch(void* const* d_in, const int* in_sizes, int n_in,
                              void* d_out, int out_size, void* d_ws, size_t ws_size,
                              hipStream_t stream) {
    const float* x  = (const float*)d_in[0];
    const int*   ei = (const int*)d_in[1];
    const float* W1 = (const float*)d_in[2];
    const float* b1 = (const float*)d_in[3];
    const float* W2 = (const float*)d_in[4];
    const float* b2 = (const float*)d_in[5];
    float* out = (float*)d_out;

    int*   counts     = (int*)d_ws;
    int*   offsets    = counts + OFF_OFFSETS;
    int*   bin_cursor = counts + OFF_CURSOR;
    float* dinv       = (float*)(counts + OFF_DINV);
    int2*  erec       = (int2*)(counts + OFF_EREC);
    __hip_bfloat16* H     = (__hip_bfloat16*)(counts + OFF_H);
    __hip_bfloat16* W1t   = (__hip_bfloat16*)(counts + OFF_W1T);
    __hip_bfloat16* W2t   = (__hip_bfloat16*)(counts + OFF_W2T);
    __hip_bfloat16* Haggb = (__hip_bfloat16*)(counts + OFF_HAGG);
    int*            ebin  = counts + OFF_HAGG;   // dead before agg1 writes Haggb
    __hip_bfloat16* H2p   = H;                   // padded [NN][64] bf16, reuses H after agg1

    int* blocksums = counts + OFF_H;             // scan scratch (before gemm1 writes H)
    int* blockpref = counts + OFF_H + 128;

    // 1. CSR build: count + W1t/W2t prep, then scan (offsets, dinv, bin cursor bases)
    (void)hipMemsetAsync(counts, 0, NN * sizeof(int), stream);
    count_prep<<<(NE + 255) / 256, 256, 0, stream>>>(ei + NE, counts, W1, W1t, W2, W2t);
    scan_phase1<<<SCAN_NB, SCAN_TILE, 0, stream>>>(counts, blocksums);
    scan_phase2<<<1, 128, 0, stream>>>(blocksums, blockpref);
    scan_phase3<<<SCAN_NB, SCAN_TILE, 0, stream>>>(counts, blockpref, offsets, bin_cursor, dinv);

    // 2. FUSED+INTERLEAVED: gemm1 (MFMA) + pass A coarse binning
    gemm1_passA<<<GEMM1_NB + NB_A, 256, 0, stream>>>(ei, bin_cursor, ebin, x, W1t, H);

    // 2b. pass B: within-bin sort -> erec (one block per bin, L2-local writes)
    passB<<<NBINS, 256, 0, stream>>>(offsets, ebin, dinv, erec);

    // 3. layer-1 gather (fused self-loop + bias + relu) -> Haggb (bf16)
    {
        long long threads = (long long)NN * 64;
        agg1_gather<<<(unsigned)((threads + 255) / 256), 256, 0, stream>>>(
            offsets, erec, dinv, H, b1, Haggb);
    }

    // 4. H2p = bf16(Haggb @ W2pad) via MFMA
    gemm2_mfma<<<(NN + 127) / 128, 256, 0, stream>>>(Haggb, W2t, H2p);

    // 5. layer-2 gather + self + bias + log_softmax -> out
    {
        long long threads = (long long)NN * 64;
        agg2_lsm<<<(unsigned)((threads + 255) / 256), 256, 0, stream>>>(
            offsets, erec, dinv, H2p, b2, out);
    }
}